// Round 1
// baseline (2401.496 us; speedup 1.0000x reference)
//
#include <hip/hip_runtime.h>
#include <hip/hip_bf16.h>
#include <stdint.h>

#define DEVI __device__ __forceinline__

typedef __bf16 bf16x8_t __attribute__((ext_vector_type(8)));
typedef float f32x4_t __attribute__((ext_vector_type(4)));
typedef unsigned short u16;

static constexpr int NBATCH = 16;
static constexpr int NV = 1024;
static constexpr int NE = 2048;
static constexpr int FV = 128;
static constexpr int FE = 64;
static constexpr int HID = 128;
static constexpr int NCLS = 16;

DEVI u16 f2bf(float f) { __hip_bfloat16 h = __float2bfloat16(f); return *reinterpret_cast<u16*>(&h); }
DEVI float bf2f(u16 u) { union { unsigned int i; float f; } x; x.i = ((unsigned int)u) << 16; return x.f; }

DEVI void gload_lds16(const void* g, void* l) {
  __builtin_amdgcn_global_load_lds(
      (const __attribute__((address_space(1))) unsigned int*)g,
      (__attribute__((address_space(3))) unsigned int*)l, 16, 0, 0);
}

// ---- K0: T (f32) -> T_bf (bf16, same layout) + Tt_bf (bf16, transposed) ----
__global__ void k_transpose(const float* __restrict__ T, u16* __restrict__ Tbf,
                            u16* __restrict__ Ttbf) {
  __shared__ u16 s[32][33];
  const int b = blockIdx.z;
  const int e0 = blockIdx.x * 32, v0 = blockIdx.y * 32;
  const float* Tb = T + (size_t)b * NV * NE;
  u16* T1 = Tbf + (size_t)b * NV * NE;
  u16* T2 = Ttbf + (size_t)b * NE * NV;
  const int tx = threadIdx.x & 31, ty = threadIdx.x >> 5;
  #pragma unroll
  for (int i = 0; i < 4; ++i) {
    int v = v0 + ty + i * 8;
    u16 u = f2bf(Tb[(size_t)v * NE + e0 + tx]);
    T1[(size_t)v * NE + e0 + tx] = u;
    s[ty + i * 8][tx] = u;
  }
  __syncthreads();
  #pragma unroll
  for (int i = 0; i < 4; ++i) {
    int e = e0 + ty + i * 8;
    T2[(size_t)e * NV + v0 + tx] = s[tx][ty + i * 8];
  }
}

// ---- K1: d[b,r] = sum_c In[b,r,c] * p[c] ---- (one wave per row)
__global__ void k_rowdot(const float* __restrict__ In, const float* __restrict__ p,
                         float* __restrict__ d, int R, int C) {
  const int b = blockIdx.y;
  const int w = threadIdx.x >> 6, l = threadIdx.x & 63;
  const int r = blockIdx.x * 4 + w;
  const float* row = In + ((size_t)b * R + r) * C;
  float s = 0.f;
  for (int c = l; c < C; c += 64) s += row[c] * p[c];
  #pragma unroll
  for (int o = 32; o; o >>= 1) s += __shfl_xor(s, o);
  if (l == 0) d[(size_t)b * R + r] = s;
}

// ---- K2: Asc[bi, r, k] = In[bg, r, k] * d[bg, k]  (bf16 out) ----
template <bool BFIN>
__global__ void k_scale(const void* __restrict__ In, const float* __restrict__ d,
                        u16* __restrict__ Out, int K, int b0) {
  const int bi = blockIdx.y, bg = b0 + bi;
  const size_t elems = (size_t)NV * NE;
  const size_t idx = ((size_t)blockIdx.x * 256 + threadIdx.x) * 8;
  const float* dd = d + (size_t)bg * K;
  const int k = (int)(idx & (size_t)(K - 1));
  float f[8];
  if (BFIN) {
    const u16* in = (const u16*)In + (size_t)bg * elems + idx;
    uint4 raw = *(const uint4*)in;
    f[0] = bf2f(raw.x & 0xffff); f[1] = bf2f(raw.x >> 16);
    f[2] = bf2f(raw.y & 0xffff); f[3] = bf2f(raw.y >> 16);
    f[4] = bf2f(raw.z & 0xffff); f[5] = bf2f(raw.z >> 16);
    f[6] = bf2f(raw.w & 0xffff); f[7] = bf2f(raw.w >> 16);
  } else {
    const float* in = (const float*)In + (size_t)bg * elems + idx;
    float4 a0 = *(const float4*)in, a1 = *(const float4*)(in + 4);
    f[0] = a0.x; f[1] = a0.y; f[2] = a0.z; f[3] = a0.w;
    f[4] = a1.x; f[5] = a1.y; f[6] = a1.z; f[7] = a1.w;
  }
  u16 o[8];
  #pragma unroll
  for (int t = 0; t < 8; ++t) o[t] = f2bf(f[t] * dd[k + t]);
  *(uint4*)((u16*)Out + (size_t)bi * elems + idx) = *(uint4*)o;
}

// ---- K3/K6: C = A (bf16, MxK) * B^T (bf16, stored N-rows x K), MFMA 16x16x32 ----
// EPI 0: P[bi] = (diag?1:acc) * adj[bg]  (bf16 store, M==N)
// EPI 1: Fout[bg] = relu(acc + bias)  (f32, width Ncols)
// EPI 2: Fout[bg] = acc + bias
template <int EPI>
__global__ __launch_bounds__(256) void k_gemm(
    const u16* __restrict__ A, size_t sA, int ldA,
    const u16* __restrict__ Bm, size_t sB, int ldB,
    int M, int K, int Nrows, int Ncols,
    const float* __restrict__ adj, u16* __restrict__ Pout,
    const float* __restrict__ bias, float* __restrict__ Fout, int b0) {
  __shared__ __align__(16) u16 As[128 * 32];
  __shared__ __align__(16) u16 Bs[128 * 32];
  const int bi = blockIdx.z, bg = b0 + bi;
  const u16* Ab = A + (size_t)bi * sA;
  const u16* Bb = Bm + (size_t)bg * sB;
  const int tm = blockIdx.y * 128, tn = blockIdx.x * 128;
  const int tid = threadIdx.x, w = tid >> 6, l = tid & 63;
  const int wm = (w >> 1) * 64, wn = (w & 1) * 64;
  const int lr = l & 15, kg = (l >> 4) * 8;
  const int chunk = l & 3;
  int arow[2], brow[2];
  #pragma unroll
  for (int i = 0; i < 2; ++i) {
    int r = (i * 4 + w) * 16 + (l >> 2);
    arow[i] = tm + r;
    int rb = tn + r;
    brow[i] = rb < Nrows ? rb : Nrows - 1;
  }
  f32x4_t acc[4][4];
  const f32x4_t zv = {0.f, 0.f, 0.f, 0.f};
  #pragma unroll
  for (int m = 0; m < 4; ++m)
    #pragma unroll
    for (int n = 0; n < 4; ++n) acc[m][n] = zv;

  for (int k0 = 0; k0 < K; k0 += 32) {
    __syncthreads();
    #pragma unroll
    for (int i = 0; i < 2; ++i) {
      gload_lds16(Ab + (size_t)arow[i] * ldA + k0 + chunk * 8, (char*)As + (i * 4 + w) * 1024);
      gload_lds16(Bb + (size_t)brow[i] * ldB + k0 + chunk * 8, (char*)Bs + (i * 4 + w) * 1024);
    }
    __syncthreads();
    bf16x8_t af[4], bfr[4];
    #pragma unroll
    for (int m = 0; m < 4; ++m) af[m] = *(const bf16x8_t*)&As[(wm + m * 16 + lr) * 32 + kg];
    #pragma unroll
    for (int n = 0; n < 4; ++n) bfr[n] = *(const bf16x8_t*)&Bs[(wn + n * 16 + lr) * 32 + kg];
    #pragma unroll
    for (int m = 0; m < 4; ++m)
      #pragma unroll
      for (int n = 0; n < 4; ++n)
        acc[m][n] = __builtin_amdgcn_mfma_f32_16x16x32_bf16(af[m], bfr[n], acc[m][n], 0, 0, 0);
  }

  if (EPI == 0) {
    const float* adjb = adj + (size_t)bg * M * M;
    u16* Pb = Pout + (size_t)bi * M * M;
    #pragma unroll
    for (int m = 0; m < 4; ++m)
      #pragma unroll
      for (int n = 0; n < 4; ++n)
        #pragma unroll
        for (int q = 0; q < 4; ++q) {
          int row = tm + wm + m * 16 + (l >> 4) * 4 + q;
          int col = tn + wn + n * 16 + lr;
          float v = acc[m][n][q];
          if (row == col) v = 1.0f;
          v *= adjb[(size_t)row * M + col];
          Pb[(size_t)row * M + col] = f2bf(v);
        }
  } else {
    float* Ob = Fout + (size_t)bg * M * Ncols;
    #pragma unroll
    for (int m = 0; m < 4; ++m)
      #pragma unroll
      for (int n = 0; n < 4; ++n)
        #pragma unroll
        for (int q = 0; q < 4; ++q) {
          int row = tm + wm + m * 16 + (l >> 4) * 4 + q;
          int col = tn + wn + n * 16 + lr;
          if (col < Ncols) {
            float v = acc[m][n][q] + bias[col];
            if (EPI == 1) v = fmaxf(v, 0.f);
            Ob[(size_t)row * Ncols + col] = v;
          }
        }
  }
}

// ---- K4: c[bg, j] = max_i P[bi, i, j] ----
__global__ void k_colmax(const u16* __restrict__ P, float* __restrict__ c,
                         int M, int N, int b0) {
  const int bi = blockIdx.y, bg = b0 + bi;
  const u16* Pb = P + (size_t)bi * M * N;
  const int j = (blockIdx.x * 256 + threadIdx.x) * 4;
  float m0 = -1e30f, m1 = -1e30f, m2 = -1e30f, m3 = -1e30f;
  for (int i = 0; i < M; ++i) {
    uint2 v = *(const uint2*)(Pb + (size_t)i * N + j);
    m0 = fmaxf(m0, bf2f(v.x & 0xffff)); m1 = fmaxf(m1, bf2f(v.x >> 16));
    m2 = fmaxf(m2, bf2f(v.y & 0xffff)); m3 = fmaxf(m3, bf2f(v.y >> 16));
  }
  float* cb = c + (size_t)bg * N;
  cb[j] = m0; cb[j + 1] = m1; cb[j + 2] = m2; cb[j + 3] = m3;
}

// ---- K5: YT[bg, c, j] = bf16( (sum_k Xin[bg,j,k] W[k,c]) / cmax[bg,j] ) ----
template <bool RELU_IN>
__global__ __launch_bounds__(256) void k_smallgemm(
    const float* __restrict__ X, size_t sX, int Kd,
    const float* __restrict__ W, int Cc,
    const float* __restrict__ cmax, u16* __restrict__ YT, size_t sY,
    int Nj, int b0) {
  __shared__ float Xs[64][129];
  __shared__ float Ws[128][33];
  const int bg = b0 + blockIdx.y;
  const float* Xb = X + (size_t)bg * sX;
  const int j0 = blockIdx.x * 64;
  const int tid = threadIdx.x;
  for (int idx = tid; idx < 64 * (Kd / 4); idx += 256) {
    int r = idx / (Kd / 4), q = idx % (Kd / 4);
    float4 v = *(const float4*)(Xb + (size_t)(j0 + r) * Kd + q * 4);
    if (RELU_IN) {
      v.x = fmaxf(v.x, 0.f); v.y = fmaxf(v.y, 0.f);
      v.z = fmaxf(v.z, 0.f); v.w = fmaxf(v.w, 0.f);
    }
    Xs[r][q * 4 + 0] = v.x; Xs[r][q * 4 + 1] = v.y;
    Xs[r][q * 4 + 2] = v.z; Xs[r][q * 4 + 3] = v.w;
  }
  const int r = tid & 63, cg = tid >> 6;
  const float rinv = 1.0f / cmax[(size_t)bg * Nj + j0 + r];
  for (int c0 = 0; c0 < Cc; c0 += 32) {
    __syncthreads();
    for (int idx = tid; idx < Kd * 32; idx += 256) {
      int k = idx >> 5, c = c0 + (idx & 31);
      Ws[k][idx & 31] = (c < Cc) ? W[(size_t)k * Cc + c] : 0.f;
    }
    __syncthreads();
    float acc[8] = {0.f, 0.f, 0.f, 0.f, 0.f, 0.f, 0.f, 0.f};
    for (int k = 0; k < Kd; ++k) {
      float xv = Xs[r][k];
      #pragma unroll
      for (int cc = 0; cc < 8; ++cc) acc[cc] += xv * Ws[k][cg * 8 + cc];
    }
    #pragma unroll
    for (int cc = 0; cc < 8; ++cc) {
      int c = c0 + cg * 8 + cc;
      if (c < Cc) YT[(size_t)bg * sY + (size_t)c * Nj + j0 + r] = f2bf(acc[cc] * rinv);
    }
  }
}

extern "C" void kernel_launch(void* const* d_in, const int* in_sizes, int n_in,
                              void* d_out, int out_size, void* d_ws, size_t ws_size,
                              hipStream_t stream) {
  const float* X    = (const float*)d_in[0];
  const float* Z    = (const float*)d_in[1];
  const float* adje = (const float*)d_in[2];
  const float* adjv = (const float*)d_in[3];
  const float* T    = (const float*)d_in[4];
  const float* W1   = (const float*)d_in[5];
  const float* b1   = (const float*)d_in[6];
  const float* p1   = (const float*)d_in[7];
  const float* W2   = (const float*)d_in[8];
  const float* b2   = (const float*)d_in[9];
  const float* p2   = (const float*)d_in[10];
  const float* W3   = (const float*)d_in[11];
  const float* b3   = (const float*)d_in[12];
  const float* p3   = (const float*)d_in[13];
  float* out = (float*)d_out;
  (void)in_sizes; (void)n_in; (void)out_size;

  char* ws = (char*)d_ws;
  size_t off = 0;
  auto alloc = [&](size_t n) -> char* {
    char* p = ws + off; off = (off + n + 255) & ~(size_t)255; return p;
  };
  u16* Tbf    = (u16*)alloc((size_t)NBATCH * NV * NE * 2);
  u16* Ttbf   = (u16*)alloc((size_t)NBATCH * NE * NV * 2);
  float* dbuf = (float*)alloc((size_t)NBATCH * NE * 4);
  float* cbuf = (float*)alloc((size_t)NBATCH * NE * 4);
  u16* YT     = (u16*)alloc((size_t)NBATCH * NE * 64 * 2);
  float* x1   = (float*)alloc((size_t)NBATCH * NV * HID * 4);
  float* z2   = (float*)alloc((size_t)NBATCH * NE * FE * 4);
  const size_t needA = (size_t)NBATCH * NV * NE * 2;
  const size_t needP = (size_t)NBATCH * NE * NE * 2;
  const bool full = (ws_size >= off + needA + needP + 1024);
  const int nb = full ? NBATCH : 1;
  u16* Asc = (u16*)alloc(full ? needA : (size_t)NV * NE * 2);
  u16* P   = (u16*)alloc(full ? needP : (size_t)NE * NE * 2);

  const dim3 blk(256, 1, 1);

  k_transpose<<<dim3(NE / 32, NV / 32, NBATCH), blk, 0, stream>>>(T, Tbf, Ttbf);

  // ---------------- Layer 1 (node: Fv -> H) ----------------
  k_rowdot<<<dim3(NE / 4, NBATCH), blk, 0, stream>>>(Z, p1, dbuf, NE, FE);
  for (int b0 = 0; b0 < NBATCH; b0 += nb) {
    k_scale<false><<<dim3((NV * NE) / 2048, nb), blk, 0, stream>>>(T, dbuf, Asc, NE, b0);
    k_gemm<0><<<dim3(NV / 128, NV / 128, nb), blk, 0, stream>>>(
        Asc, (size_t)NV * NE, NE, Tbf, (size_t)NV * NE, NE,
        NV, NE, NV, 0, adjv, P, nullptr, nullptr, b0);
    k_colmax<<<dim3(NV / 1024, nb), blk, 0, stream>>>(P, cbuf, NV, NV, b0);
    k_smallgemm<false><<<dim3(NV / 64, nb), blk, 0, stream>>>(
        X, (size_t)NV * FV, FV, W1, HID, cbuf, YT, (size_t)NV * HID, NV, b0);
    k_gemm<1><<<dim3(1, NV / 128, nb), blk, 0, stream>>>(
        P, (size_t)NV * NV, NV, YT, (size_t)NV * HID, NV,
        NV, NV, HID, HID, nullptr, nullptr, b1, x1, b0);
  }
  // ---------------- Layer 2 (edge: Fe -> Fe) ----------------
  k_rowdot<<<dim3(NV / 4, NBATCH), blk, 0, stream>>>(x1, p2, dbuf, NV, HID);
  for (int b0 = 0; b0 < NBATCH; b0 += nb) {
    k_scale<true><<<dim3((NE * NV) / 2048, nb), blk, 0, stream>>>(Ttbf, dbuf, Asc, NV, b0);
    k_gemm<0><<<dim3(NE / 128, NE / 128, nb), blk, 0, stream>>>(
        Asc, (size_t)NE * NV, NV, Ttbf, (size_t)NE * NV, NV,
        NE, NV, NE, 0, adje, P, nullptr, nullptr, b0);
    k_colmax<<<dim3(NE / 1024, nb), blk, 0, stream>>>(P, cbuf, NE, NE, b0);
    k_smallgemm<true><<<dim3(NE / 64, nb), blk, 0, stream>>>(
        Z, (size_t)NE * FE, FE, W2, FE, cbuf, YT, (size_t)NE * FE, NE, b0);
    k_gemm<1><<<dim3(1, NE / 128, nb), blk, 0, stream>>>(
        P, (size_t)NE * NE, NE, YT, (size_t)NE * FE, NE,
        NE, NE, FE, FE, nullptr, nullptr, b2, z2, b0);
  }
  // ---------------- Layer 3 (node: H -> C) ----------------
  k_rowdot<<<dim3(NE / 4, NBATCH), blk, 0, stream>>>(z2, p3, dbuf, NE, FE);
  for (int b0 = 0; b0 < NBATCH; b0 += nb) {
    k_scale<false><<<dim3((NV * NE) / 2048, nb), blk, 0, stream>>>(T, dbuf, Asc, NE, b0);
    k_gemm<0><<<dim3(NV / 128, NV / 128, nb), blk, 0, stream>>>(
        Asc, (size_t)NV * NE, NE, Tbf, (size_t)NV * NE, NE,
        NV, NE, NV, 0, adjv, P, nullptr, nullptr, b0);
    k_colmax<<<dim3(NV / 1024, nb), blk, 0, stream>>>(P, cbuf, NV, NV, b0);
    k_smallgemm<false><<<dim3(NV / 64, nb), blk, 0, stream>>>(
        x1, (size_t)NV * HID, HID, W3, NCLS, cbuf, YT, (size_t)NV * NCLS, NV, b0);
    k_gemm<2><<<dim3(1, NV / 128, nb), blk, 0, stream>>>(
        P, (size_t)NV * NV, NV, YT, (size_t)NV * NCLS, NV,
        NV, NV, NCLS, NCLS, nullptr, nullptr, b3, out, b0);
  }
}

// Round 2
// 1005.113 us; speedup vs baseline: 2.3893x; 2.3893x over previous
//
#include <hip/hip_runtime.h>
#include <hip/hip_bf16.h>
#include <stdint.h>

#define DEVI __device__ __forceinline__

typedef __bf16 bf16x8_t __attribute__((ext_vector_type(8)));
typedef float f32x4_t __attribute__((ext_vector_type(4)));
typedef unsigned short u16;

static constexpr int NBATCH = 16;
static constexpr int NV = 1024;
static constexpr int NE = 2048;
static constexpr int FV = 128;
static constexpr int FE = 64;
static constexpr int HID = 128;
static constexpr int NCLS = 16;

DEVI u16 f2bf(float f) { __hip_bfloat16 h = __float2bfloat16(f); return *reinterpret_cast<u16*>(&h); }
DEVI float bf2f(u16 u) { union { unsigned int i; float f; } x; x.i = ((unsigned int)u) << 16; return x.f; }

DEVI void gload_lds16(const void* g, void* l) {
  __builtin_amdgcn_global_load_lds(
      (const __attribute__((address_space(1))) unsigned int*)g,
      (__attribute__((address_space(3))) unsigned int*)l, 16, 0, 0);
}

// ---- K0: T (f32) -> T_bf (bf16, same layout) + Tt_bf (bf16, transposed) ----
__global__ void k_transpose(const float* __restrict__ T, u16* __restrict__ Tbf,
                            u16* __restrict__ Ttbf) {
  __shared__ u16 s[32][33];
  const int b = blockIdx.z;
  const int e0 = blockIdx.x * 32, v0 = blockIdx.y * 32;
  const float* Tb = T + (size_t)b * NV * NE;
  u16* T1 = Tbf + (size_t)b * NV * NE;
  u16* T2 = Ttbf + (size_t)b * NE * NV;
  const int tx = threadIdx.x & 31, ty = threadIdx.x >> 5;
  #pragma unroll
  for (int i = 0; i < 4; ++i) {
    int v = v0 + ty + i * 8;
    u16 u = f2bf(Tb[(size_t)v * NE + e0 + tx]);
    T1[(size_t)v * NE + e0 + tx] = u;
    s[ty + i * 8][tx] = u;
  }
  __syncthreads();
  #pragma unroll
  for (int i = 0; i < 4; ++i) {
    int e = e0 + ty + i * 8;
    T2[(size_t)e * NV + v0 + tx] = s[tx][ty + i * 8];
  }
}

// ---- K1: d[b,r] = sum_c In[b,r,c] * p[c] ---- (one wave per row)
__global__ void k_rowdot(const float* __restrict__ In, const float* __restrict__ p,
                         float* __restrict__ d, int R, int C) {
  const int b = blockIdx.y;
  const int w = threadIdx.x >> 6, l = threadIdx.x & 63;
  const int r = blockIdx.x * 4 + w;
  const float* row = In + ((size_t)b * R + r) * C;
  float s = 0.f;
  for (int c = l; c < C; c += 64) s += row[c] * p[c];
  #pragma unroll
  for (int o = 32; o; o >>= 1) s += __shfl_xor(s, o);
  if (l == 0) d[(size_t)b * R + r] = s;
}

// ---- K2: Asc[bi, r, k] = In[bg, r, k] * d[bg, k]  (bf16 out) ----
template <bool BFIN>
__global__ void k_scale(const void* __restrict__ In, const float* __restrict__ d,
                        u16* __restrict__ Out, int K, int b0) {
  const int bi = blockIdx.y, bg = b0 + bi;
  const size_t elems = (size_t)NV * NE;
  const size_t idx = ((size_t)blockIdx.x * 256 + threadIdx.x) * 8;
  const float* dd = d + (size_t)bg * K;
  const int k = (int)(idx & (size_t)(K - 1));
  float f[8];
  if (BFIN) {
    const u16* in = (const u16*)In + (size_t)bg * elems + idx;
    uint4 raw = *(const uint4*)in;
    f[0] = bf2f(raw.x & 0xffff); f[1] = bf2f(raw.x >> 16);
    f[2] = bf2f(raw.y & 0xffff); f[3] = bf2f(raw.y >> 16);
    f[4] = bf2f(raw.z & 0xffff); f[5] = bf2f(raw.z >> 16);
    f[6] = bf2f(raw.w & 0xffff); f[7] = bf2f(raw.w >> 16);
  } else {
    const float* in = (const float*)In + (size_t)bg * elems + idx;
    float4 a0 = *(const float4*)in, a1 = *(const float4*)(in + 4);
    f[0] = a0.x; f[1] = a0.y; f[2] = a0.z; f[3] = a0.w;
    f[4] = a1.x; f[5] = a1.y; f[6] = a1.z; f[7] = a1.w;
  }
  u16 o[8];
  #pragma unroll
  for (int t = 0; t < 8; ++t) o[t] = f2bf(f[t] * dd[k + t]);
  *(uint4*)((u16*)Out + (size_t)bi * elems + idx) = *(uint4*)o;
}

// ---- K3/K6: C = A (bf16, MxK) * B^T (bf16, stored N-rows x K), MFMA 16x16x32 ----
// EPI 0: P[bi] = (diag?1:acc) * adj[bg]  (bf16 store, M==N)
// EPI 1: Fout[bg] = relu(acc + bias)  (f32, width Ncols)
// EPI 2: Fout[bg] = acc + bias
template <int EPI>
__global__ __launch_bounds__(256) void k_gemm(
    const u16* __restrict__ A, size_t sA, int ldA,
    const u16* __restrict__ Bm, size_t sB, int ldB,
    int M, int K, int Nrows, int Ncols,
    const float* __restrict__ adj, u16* __restrict__ Pout,
    const float* __restrict__ bias, float* __restrict__ Fout, int b0) {
  __shared__ __align__(16) u16 As[128 * 32];
  __shared__ __align__(16) u16 Bs[128 * 32];
  const int bi = blockIdx.z, bg = b0 + bi;
  const u16* Ab = A + (size_t)bi * sA;
  const u16* Bb = Bm + (size_t)bg * sB;
  const int tm = blockIdx.y * 128, tn = blockIdx.x * 128;
  const int tid = threadIdx.x, w = tid >> 6, l = tid & 63;
  const int wm = (w >> 1) * 64, wn = (w & 1) * 64;
  const int lr = l & 15, kg = (l >> 4) * 8;
  const int chunk = l & 3;
  int arow[2], brow[2];
  #pragma unroll
  for (int i = 0; i < 2; ++i) {
    int r = (i * 4 + w) * 16 + (l >> 2);
    arow[i] = tm + r;
    int rb = tn + r;
    brow[i] = rb < Nrows ? rb : Nrows - 1;
  }
  f32x4_t acc[4][4];
  const f32x4_t zv = {0.f, 0.f, 0.f, 0.f};
  #pragma unroll
  for (int m = 0; m < 4; ++m)
    #pragma unroll
    for (int n = 0; n < 4; ++n) acc[m][n] = zv;

  for (int k0 = 0; k0 < K; k0 += 32) {
    __syncthreads();
    #pragma unroll
    for (int i = 0; i < 2; ++i) {
      gload_lds16(Ab + (size_t)arow[i] * ldA + k0 + chunk * 8, (char*)As + (i * 4 + w) * 1024);
      gload_lds16(Bb + (size_t)brow[i] * ldB + k0 + chunk * 8, (char*)Bs + (i * 4 + w) * 1024);
    }
    __syncthreads();
    bf16x8_t af[4], bfr[4];
    #pragma unroll
    for (int m = 0; m < 4; ++m) af[m] = *(const bf16x8_t*)&As[(wm + m * 16 + lr) * 32 + kg];
    #pragma unroll
    for (int n = 0; n < 4; ++n) bfr[n] = *(const bf16x8_t*)&Bs[(wn + n * 16 + lr) * 32 + kg];
    #pragma unroll
    for (int m = 0; m < 4; ++m)
      #pragma unroll
      for (int n = 0; n < 4; ++n)
        acc[m][n] = __builtin_amdgcn_mfma_f32_16x16x32_bf16(af[m], bfr[n], acc[m][n], 0, 0, 0);
  }

  if (EPI == 0) {
    const float* adjb = adj + (size_t)bg * M * M;
    u16* Pb = Pout + (size_t)bi * M * M;
    #pragma unroll
    for (int m = 0; m < 4; ++m)
      #pragma unroll
      for (int n = 0; n < 4; ++n)
        #pragma unroll
        for (int q = 0; q < 4; ++q) {
          int row = tm + wm + m * 16 + (l >> 4) * 4 + q;
          int col = tn + wn + n * 16 + lr;
          float v = acc[m][n][q];
          if (row == col) v = 1.0f;
          v *= adjb[(size_t)row * M + col];
          Pb[(size_t)row * M + col] = f2bf(v);
        }
  } else {
    float* Ob = Fout + (size_t)bg * M * Ncols;
    #pragma unroll
    for (int m = 0; m < 4; ++m)
      #pragma unroll
      for (int n = 0; n < 4; ++n)
        #pragma unroll
        for (int q = 0; q < 4; ++q) {
          int row = tm + wm + m * 16 + (l >> 4) * 4 + q;
          int col = tn + wn + n * 16 + lr;
          if (col < Ncols) {
            float v = acc[m][n][q] + bias[col];
            if (EPI == 1) v = fmaxf(v, 0.f);
            Ob[(size_t)row * Ncols + col] = v;
          }
        }
  }
}

// ---- K4: c[bg, j] = max_i P[bi, i, j]  (row-sliced, atomicMax on float bits) ----
// True col max is always > 0 (diag entry = adj > 0), so clamping partials at 0
// and using uint atomicMax on float bit patterns is exact.
__global__ void k_colmax(const u16* __restrict__ P, unsigned int* __restrict__ c,
                         int M, int N, int rowsPer, int b0) {
  const int bi = blockIdx.z, bg = b0 + bi;
  const u16* Pb = P + (size_t)bi * (size_t)M * N;
  const int j = (blockIdx.x * 256 + threadIdx.x) * 4;
  const int r0 = blockIdx.y * rowsPer;
  float m0 = 0.f, m1 = 0.f, m2 = 0.f, m3 = 0.f;
  for (int i = r0; i < r0 + rowsPer; ++i) {
    uint2 v = *(const uint2*)(Pb + (size_t)i * N + j);
    m0 = fmaxf(m0, bf2f(v.x & 0xffff)); m1 = fmaxf(m1, bf2f(v.x >> 16));
    m2 = fmaxf(m2, bf2f(v.y & 0xffff)); m3 = fmaxf(m3, bf2f(v.y >> 16));
  }
  unsigned int* cb = c + (size_t)bg * N;
  atomicMax(cb + j + 0, __float_as_uint(m0));
  atomicMax(cb + j + 1, __float_as_uint(m1));
  atomicMax(cb + j + 2, __float_as_uint(m2));
  atomicMax(cb + j + 3, __float_as_uint(m3));
}

// ---- K5: YT[bg, c, j] = bf16( (sum_k Xin[bg,j,k] W[k,c]) / cmax[bg,j] ) ----
template <bool RELU_IN>
__global__ __launch_bounds__(256) void k_smallgemm(
    const float* __restrict__ X, size_t sX, int Kd,
    const float* __restrict__ W, int Cc,
    const float* __restrict__ cmax, u16* __restrict__ YT, size_t sY,
    int Nj, int b0) {
  __shared__ float Xs[64][129];
  __shared__ float Ws[128][33];
  const int bg = b0 + blockIdx.y;
  const float* Xb = X + (size_t)bg * sX;
  const int j0 = blockIdx.x * 64;
  const int tid = threadIdx.x;
  for (int idx = tid; idx < 64 * (Kd / 4); idx += 256) {
    int r = idx / (Kd / 4), q = idx % (Kd / 4);
    float4 v = *(const float4*)(Xb + (size_t)(j0 + r) * Kd + q * 4);
    if (RELU_IN) {
      v.x = fmaxf(v.x, 0.f); v.y = fmaxf(v.y, 0.f);
      v.z = fmaxf(v.z, 0.f); v.w = fmaxf(v.w, 0.f);
    }
    Xs[r][q * 4 + 0] = v.x; Xs[r][q * 4 + 1] = v.y;
    Xs[r][q * 4 + 2] = v.z; Xs[r][q * 4 + 3] = v.w;
  }
  const int r = tid & 63, cg = tid >> 6;
  const float rinv = 1.0f / cmax[(size_t)bg * Nj + j0 + r];
  for (int c0 = 0; c0 < Cc; c0 += 32) {
    __syncthreads();
    for (int idx = tid; idx < Kd * 32; idx += 256) {
      int k = idx >> 5, c = c0 + (idx & 31);
      Ws[k][idx & 31] = (c < Cc) ? W[(size_t)k * Cc + c] : 0.f;
    }
    __syncthreads();
    float acc[8] = {0.f, 0.f, 0.f, 0.f, 0.f, 0.f, 0.f, 0.f};
    for (int k = 0; k < Kd; ++k) {
      float xv = Xs[r][k];
      #pragma unroll
      for (int cc = 0; cc < 8; ++cc) acc[cc] += xv * Ws[k][cg * 8 + cc];
    }
    #pragma unroll
    for (int cc = 0; cc < 8; ++cc) {
      int c = c0 + cg * 8 + cc;
      if (c < Cc) YT[(size_t)bg * sY + (size_t)c * Nj + j0 + r] = f2bf(acc[cc] * rinv);
    }
  }
}

extern "C" void kernel_launch(void* const* d_in, const int* in_sizes, int n_in,
                              void* d_out, int out_size, void* d_ws, size_t ws_size,
                              hipStream_t stream) {
  const float* X    = (const float*)d_in[0];
  const float* Z    = (const float*)d_in[1];
  const float* adje = (const float*)d_in[2];
  const float* adjv = (const float*)d_in[3];
  const float* T    = (const float*)d_in[4];
  const float* W1   = (const float*)d_in[5];
  const float* b1   = (const float*)d_in[6];
  const float* p1   = (const float*)d_in[7];
  const float* W2   = (const float*)d_in[8];
  const float* b2   = (const float*)d_in[9];
  const float* p2   = (const float*)d_in[10];
  const float* W3   = (const float*)d_in[11];
  const float* b3   = (const float*)d_in[12];
  const float* p3   = (const float*)d_in[13];
  float* out = (float*)d_out;
  (void)in_sizes; (void)n_in; (void)out_size;

  char* ws = (char*)d_ws;
  size_t off = 0;
  auto alloc = [&](size_t n) -> char* {
    char* p = ws + off; off = (off + n + 255) & ~(size_t)255; return p;
  };
  u16* Tbf    = (u16*)alloc((size_t)NBATCH * NV * NE * 2);
  u16* Ttbf   = (u16*)alloc((size_t)NBATCH * NE * NV * 2);
  float* dbuf = (float*)alloc((size_t)NBATCH * NE * 4);
  float* cbuf = (float*)alloc((size_t)NBATCH * NE * 4);
  u16* YT     = (u16*)alloc((size_t)NBATCH * NE * 64 * 2);
  float* x1   = (float*)alloc((size_t)NBATCH * NV * HID * 4);
  float* z2   = (float*)alloc((size_t)NBATCH * NE * FE * 4);
  const size_t needA = (size_t)NBATCH * NV * NE * 2;
  const size_t needP = (size_t)NBATCH * NE * NE * 2;
  const bool full = (ws_size >= off + needA + needP + 1024);
  const int nb = full ? NBATCH : 1;
  u16* Asc = (u16*)alloc(full ? needA : (size_t)NV * NE * 2);
  u16* P   = (u16*)alloc(full ? needP : (size_t)NE * NE * 2);

  const dim3 blk(256, 1, 1);
  const size_t cbytes = (size_t)NBATCH * NE * 4;

  k_transpose<<<dim3(NE / 32, NV / 32, NBATCH), blk, 0, stream>>>(T, Tbf, Ttbf);

  // ---------------- Layer 1 (node: Fv -> H) ----------------
  k_rowdot<<<dim3(NE / 4, NBATCH), blk, 0, stream>>>(Z, p1, dbuf, NE, FE);
  for (int b0 = 0; b0 < NBATCH; b0 += nb) {
    k_scale<false><<<dim3((NV * NE) / 2048, nb), blk, 0, stream>>>(T, dbuf, Asc, NE, b0);
    k_gemm<0><<<dim3(NV / 128, NV / 128, nb), blk, 0, stream>>>(
        Asc, (size_t)NV * NE, NE, Tbf, (size_t)NV * NE, NE,
        NV, NE, NV, 0, adjv, P, nullptr, nullptr, b0);
    hipMemsetAsync(cbuf, 0, cbytes, stream);
    k_colmax<<<dim3(NV / 1024, NV / 32, nb), blk, 0, stream>>>(
        P, (unsigned int*)cbuf, NV, NV, 32, b0);
    k_smallgemm<false><<<dim3(NV / 64, nb), blk, 0, stream>>>(
        X, (size_t)NV * FV, FV, W1, HID, cbuf, YT, (size_t)NV * HID, NV, b0);
    k_gemm<1><<<dim3(1, NV / 128, nb), blk, 0, stream>>>(
        P, (size_t)NV * NV, NV, YT, (size_t)NV * HID, NV,
        NV, NV, HID, HID, nullptr, nullptr, b1, x1, b0);
  }
  // ---------------- Layer 2 (edge: Fe -> Fe) ----------------
  k_rowdot<<<dim3(NV / 4, NBATCH), blk, 0, stream>>>(x1, p2, dbuf, NV, HID);
  for (int b0 = 0; b0 < NBATCH; b0 += nb) {
    k_scale<true><<<dim3((NE * NV) / 2048, nb), blk, 0, stream>>>(Ttbf, dbuf, Asc, NV, b0);
    k_gemm<0><<<dim3(NE / 128, NE / 128, nb), blk, 0, stream>>>(
        Asc, (size_t)NE * NV, NV, Ttbf, (size_t)NE * NV, NV,
        NE, NV, NE, 0, adje, P, nullptr, nullptr, b0);
    hipMemsetAsync(cbuf, 0, cbytes, stream);
    k_colmax<<<dim3(NE / 1024, NE / 64, nb), blk, 0, stream>>>(
        P, (unsigned int*)cbuf, NE, NE, 64, b0);
    k_smallgemm<true><<<dim3(NE / 64, nb), blk, 0, stream>>>(
        Z, (size_t)NE * FE, FE, W2, FE, cbuf, YT, (size_t)NE * FE, NE, b0);
    k_gemm<1><<<dim3(1, NE / 128, nb), blk, 0, stream>>>(
        P, (size_t)NE * NE, NE, YT, (size_t)NE * FE, NE,
        NE, NE, FE, FE, nullptr, nullptr, b2, z2, b0);
  }
  // ---------------- Layer 3 (node: H -> C) ----------------
  k_rowdot<<<dim3(NE / 4, NBATCH), blk, 0, stream>>>(z2, p3, dbuf, NE, FE);
  for (int b0 = 0; b0 < NBATCH; b0 += nb) {
    k_scale<false><<<dim3((NV * NE) / 2048, nb), blk, 0, stream>>>(T, dbuf, Asc, NE, b0);
    k_gemm<0><<<dim3(NV / 128, NV / 128, nb), blk, 0, stream>>>(
        Asc, (size_t)NV * NE, NE, Tbf, (size_t)NV * NE, NE,
        NV, NE, NV, 0, adjv, P, nullptr, nullptr, b0);
    hipMemsetAsync(cbuf, 0, cbytes, stream);
    k_colmax<<<dim3(NV / 1024, NV / 32, nb), blk, 0, stream>>>(
        P, (unsigned int*)cbuf, NV, NV, 32, b0);
    k_smallgemm<false><<<dim3(NV / 64, nb), blk, 0, stream>>>(
        x1, (size_t)NV * HID, HID, W3, NCLS, cbuf, YT, (size_t)NV * NCLS, NV, b0);
    k_gemm<2><<<dim3(1, NV / 128, nb), blk, 0, stream>>>(
        P, (size_t)NV * NV, NV, YT, (size_t)NV * NCLS, NV,
        NV, NV, NCLS, NCLS, nullptr, nullptr, b3, out, b0);
  }
}

// Round 3
// 981.232 us; speedup vs baseline: 2.4474x; 1.0243x over previous
//
#include <hip/hip_runtime.h>
#include <hip/hip_bf16.h>
#include <stdint.h>

#define DEVI __device__ __forceinline__

typedef __bf16 bf16x8_t __attribute__((ext_vector_type(8)));
typedef float f32x4_t __attribute__((ext_vector_type(4)));
typedef unsigned short u16;

static constexpr int NBATCH = 16;
static constexpr int NV = 1024;
static constexpr int NE = 2048;
static constexpr int FV = 128;
static constexpr int FE = 64;
static constexpr int HID = 128;
static constexpr int NCLS = 16;

DEVI u16 f2bf(float f) { __hip_bfloat16 h = __float2bfloat16(f); return *reinterpret_cast<u16*>(&h); }
DEVI float bf2f(u16 u) { union { unsigned int i; float f; } x; x.i = ((unsigned int)u) << 16; return x.f; }

DEVI void gload_lds16(const void* g, void* l) {
  __builtin_amdgcn_global_load_lds(
      (const __attribute__((address_space(1))) unsigned int*)g,
      (__attribute__((address_space(3))) unsigned int*)l, 16, 0, 0);
}

// ---- K0: T (f32) -> T_bf (bf16, same layout) + Tt_bf (bf16, transposed) ----
__global__ void k_transpose(const float* __restrict__ T, u16* __restrict__ Tbf,
                            u16* __restrict__ Ttbf) {
  __shared__ u16 s[32][33];
  const int b = blockIdx.z;
  const int e0 = blockIdx.x * 32, v0 = blockIdx.y * 32;
  const float* Tb = T + (size_t)b * NV * NE;
  u16* T1 = Tbf + (size_t)b * NV * NE;
  u16* T2 = Ttbf + (size_t)b * NE * NV;
  const int tx = threadIdx.x & 31, ty = threadIdx.x >> 5;
  #pragma unroll
  for (int i = 0; i < 4; ++i) {
    int v = v0 + ty + i * 8;
    u16 u = f2bf(Tb[(size_t)v * NE + e0 + tx]);
    T1[(size_t)v * NE + e0 + tx] = u;
    s[ty + i * 8][tx] = u;
  }
  __syncthreads();
  #pragma unroll
  for (int i = 0; i < 4; ++i) {
    int e = e0 + ty + i * 8;
    T2[(size_t)e * NV + v0 + tx] = s[tx][ty + i * 8];
  }
}

// ---- K1: d[b,r] = sum_c In[b,r,c] * p[c] ---- (one wave per row)
__global__ void k_rowdot(const float* __restrict__ In, const float* __restrict__ p,
                         float* __restrict__ d, int R, int C) {
  const int b = blockIdx.y;
  const int w = threadIdx.x >> 6, l = threadIdx.x & 63;
  const int r = blockIdx.x * 4 + w;
  const float* row = In + ((size_t)b * R + r) * C;
  float s = 0.f;
  for (int c = l; c < C; c += 64) s += row[c] * p[c];
  #pragma unroll
  for (int o = 32; o; o >>= 1) s += __shfl_xor(s, o);
  if (l == 0) d[(size_t)b * R + r] = s;
}

// ---- K2: Asc[bi, r, k] = In[bg, r, k] * d[bg, k]  (bf16 out) ----
template <bool BFIN>
__global__ void k_scale(const void* __restrict__ In, const float* __restrict__ d,
                        u16* __restrict__ Out, int K, int b0) {
  const int bi = blockIdx.y, bg = b0 + bi;
  const size_t elems = (size_t)NV * NE;
  const size_t idx = ((size_t)blockIdx.x * 256 + threadIdx.x) * 8;
  const float* dd = d + (size_t)bg * K;
  const int k = (int)(idx & (size_t)(K - 1));
  float f[8];
  if (BFIN) {
    const u16* in = (const u16*)In + (size_t)bg * elems + idx;
    uint4 raw = *(const uint4*)in;
    f[0] = bf2f(raw.x & 0xffff); f[1] = bf2f(raw.x >> 16);
    f[2] = bf2f(raw.y & 0xffff); f[3] = bf2f(raw.y >> 16);
    f[4] = bf2f(raw.z & 0xffff); f[5] = bf2f(raw.z >> 16);
    f[6] = bf2f(raw.w & 0xffff); f[7] = bf2f(raw.w >> 16);
  } else {
    const float* in = (const float*)In + (size_t)bg * elems + idx;
    float4 a0 = *(const float4*)in, a1 = *(const float4*)(in + 4);
    f[0] = a0.x; f[1] = a0.y; f[2] = a0.z; f[3] = a0.w;
    f[4] = a1.x; f[5] = a1.y; f[6] = a1.z; f[7] = a1.w;
  }
  u16 o[8];
  #pragma unroll
  for (int t = 0; t < 8; ++t) o[t] = f2bf(f[t] * dd[k + t]);
  *(uint4*)((u16*)Out + (size_t)bi * elems + idx) = *(uint4*)o;
}

// ---- K3: C = A (bf16, MxK) * B^T (bf16, stored N-rows x K), MFMA 16x16x32 ----
// Software-pipelined (T3 minimum 2-phase): stage(next) issued BEFORE
// ds_read+MFMA of cur; one __syncthreads per K-step drains vmcnt.
// EPI 0: P[bi] = (diag?1:acc)*adj[bg] (bf16) + fused column-max atomics
// EPI 1: Fout[bg] = relu(acc + bias)  (f32, width Ncols)
// EPI 2: Fout[bg] = acc + bias
template <int EPI>
__global__ __launch_bounds__(256) void k_gemm(
    const u16* __restrict__ A, size_t sA, int ldA,
    const u16* __restrict__ Bm, size_t sB, int ldB,
    int M, int K, int Nrows, int Ncols,
    const float* __restrict__ adj, u16* __restrict__ Pout,
    unsigned int* __restrict__ cmaxOut,
    const float* __restrict__ bias, float* __restrict__ Fout, int b0) {
  __shared__ __align__(16) u16 As[2][128 * 32];
  __shared__ __align__(16) u16 Bs[2][128 * 32];
  const int bi = blockIdx.z, bg = b0 + bi;
  const u16* Ab = A + (size_t)bi * sA;
  const u16* Bb = Bm + (size_t)bg * sB;
  const int tm = blockIdx.y * 128, tn = blockIdx.x * 128;
  const int tid = threadIdx.x, w = tid >> 6, l = tid & 63;
  const int wm = (w >> 1) * 64, wn = (w & 1) * 64;
  const int lr = l & 15, kg = (l >> 4) * 8;
  const int chunk = l & 3;
  int arow[2], brow[2];
  #pragma unroll
  for (int i = 0; i < 2; ++i) {
    int r = (i * 4 + w) * 16 + (l >> 2);
    arow[i] = tm + r;
    int rb = tn + r;
    brow[i] = rb < Nrows ? rb : Nrows - 1;
  }
  f32x4_t acc[4][4];
  const f32x4_t zv = {0.f, 0.f, 0.f, 0.f};
  #pragma unroll
  for (int m = 0; m < 4; ++m)
    #pragma unroll
    for (int n = 0; n < 4; ++n) acc[m][n] = zv;

  auto stage = [&](int buf, int k0) {
    #pragma unroll
    for (int i = 0; i < 2; ++i) {
      gload_lds16(Ab + (size_t)arow[i] * ldA + k0 + chunk * 8,
                  (char*)As[buf] + (i * 4 + w) * 1024);
      gload_lds16(Bb + (size_t)brow[i] * ldB + k0 + chunk * 8,
                  (char*)Bs[buf] + (i * 4 + w) * 1024);
    }
  };

  const int nsteps = K >> 5;
  stage(0, 0);
  __syncthreads();  // vmcnt(0) drain + barrier: tile 0 resident
  for (int s = 0; s < nsteps; ++s) {
    const int cur = s & 1;
    if (s + 1 < nsteps) stage(cur ^ 1, (s + 1) << 5);  // overlap with compute
    bf16x8_t af[4], bfr[4];
    #pragma unroll
    for (int m = 0; m < 4; ++m) af[m] = *(const bf16x8_t*)&As[cur][(wm + m * 16 + lr) * 32 + kg];
    #pragma unroll
    for (int n = 0; n < 4; ++n) bfr[n] = *(const bf16x8_t*)&Bs[cur][(wn + n * 16 + lr) * 32 + kg];
    #pragma unroll
    for (int m = 0; m < 4; ++m)
      #pragma unroll
      for (int n = 0; n < 4; ++n)
        acc[m][n] = __builtin_amdgcn_mfma_f32_16x16x32_bf16(af[m], bfr[n], acc[m][n], 0, 0, 0);
    __syncthreads();  // drains next-tile stage (latency already hidden)
  }

  if (EPI == 0) {
    const float* adjb = adj + (size_t)bg * M * M;
    u16* Pb = Pout + (size_t)bi * M * M;
    unsigned int* cb = cmaxOut + (size_t)bg * M;
    #pragma unroll
    for (int n = 0; n < 4; ++n) {
      const int col = tn + wn + n * 16 + lr;
      float vmax = 0.f;
      #pragma unroll
      for (int m = 0; m < 4; ++m)
        #pragma unroll
        for (int q = 0; q < 4; ++q) {
          int row = tm + wm + m * 16 + (l >> 4) * 4 + q;
          float v = acc[m][n][q];
          if (row == col) v = 1.0f;
          v *= adjb[(size_t)row * M + col];
          vmax = fmaxf(vmax, v);
          Pb[(size_t)row * M + col] = f2bf(v);
        }
      atomicMax(cb + col, __float_as_uint(vmax));
    }
  } else {
    float* Ob = Fout + (size_t)bg * M * Ncols;
    #pragma unroll
    for (int m = 0; m < 4; ++m)
      #pragma unroll
      for (int n = 0; n < 4; ++n)
        #pragma unroll
        for (int q = 0; q < 4; ++q) {
          int row = tm + wm + m * 16 + (l >> 4) * 4 + q;
          int col = tn + wn + n * 16 + lr;
          if (col < Ncols) {
            float v = acc[m][n][q] + bias[col];
            if (EPI == 1) v = fmaxf(v, 0.f);
            Ob[(size_t)row * Ncols + col] = v;
          }
        }
  }
}

// ---- K5: YT[bg, c, j] = bf16( (sum_k Xin[bg,j,k] W[k,c]) / cmax[bg,j] ) ----
template <bool RELU_IN>
__global__ __launch_bounds__(256) void k_smallgemm(
    const float* __restrict__ X, size_t sX, int Kd,
    const float* __restrict__ W, int Cc,
    const float* __restrict__ cmax, u16* __restrict__ YT, size_t sY,
    int Nj, int b0) {
  __shared__ float Xs[64][129];
  __shared__ float Ws[128][33];
  const int bg = b0 + blockIdx.y;
  const float* Xb = X + (size_t)bg * sX;
  const int j0 = blockIdx.x * 64;
  const int tid = threadIdx.x;
  for (int idx = tid; idx < 64 * (Kd / 4); idx += 256) {
    int r = idx / (Kd / 4), q = idx % (Kd / 4);
    float4 v = *(const float4*)(Xb + (size_t)(j0 + r) * Kd + q * 4);
    if (RELU_IN) {
      v.x = fmaxf(v.x, 0.f); v.y = fmaxf(v.y, 0.f);
      v.z = fmaxf(v.z, 0.f); v.w = fmaxf(v.w, 0.f);
    }
    Xs[r][q * 4 + 0] = v.x; Xs[r][q * 4 + 1] = v.y;
    Xs[r][q * 4 + 2] = v.z; Xs[r][q * 4 + 3] = v.w;
  }
  const int r = tid & 63, cg = tid >> 6;
  const float rinv = 1.0f / cmax[(size_t)bg * Nj + j0 + r];
  for (int c0 = 0; c0 < Cc; c0 += 32) {
    __syncthreads();
    for (int idx = tid; idx < Kd * 32; idx += 256) {
      int k = idx >> 5, c = c0 + (idx & 31);
      Ws[k][idx & 31] = (c < Cc) ? W[(size_t)k * Cc + c] : 0.f;
    }
    __syncthreads();
    float acc[8] = {0.f, 0.f, 0.f, 0.f, 0.f, 0.f, 0.f, 0.f};
    for (int k = 0; k < Kd; ++k) {
      float xv = Xs[r][k];
      #pragma unroll
      for (int cc = 0; cc < 8; ++cc) acc[cc] += xv * Ws[k][cg * 8 + cc];
    }
    #pragma unroll
    for (int cc = 0; cc < 8; ++cc) {
      int c = c0 + cg * 8 + cc;
      if (c < Cc) YT[(size_t)bg * sY + (size_t)c * Nj + j0 + r] = f2bf(acc[cc] * rinv);
    }
  }
}

extern "C" void kernel_launch(void* const* d_in, const int* in_sizes, int n_in,
                              void* d_out, int out_size, void* d_ws, size_t ws_size,
                              hipStream_t stream) {
  const float* X    = (const float*)d_in[0];
  const float* Z    = (const float*)d_in[1];
  const float* adje = (const float*)d_in[2];
  const float* adjv = (const float*)d_in[3];
  const float* T    = (const float*)d_in[4];
  const float* W1   = (const float*)d_in[5];
  const float* b1   = (const float*)d_in[6];
  const float* p1   = (const float*)d_in[7];
  const float* W2   = (const float*)d_in[8];
  const float* b2   = (const float*)d_in[9];
  const float* p2   = (const float*)d_in[10];
  const float* W3   = (const float*)d_in[11];
  const float* b3   = (const float*)d_in[12];
  const float* p3   = (const float*)d_in[13];
  float* out = (float*)d_out;
  (void)in_sizes; (void)n_in; (void)out_size;

  char* ws = (char*)d_ws;
  size_t off = 0;
  auto alloc = [&](size_t n) -> char* {
    char* p = ws + off; off = (off + n + 255) & ~(size_t)255; return p;
  };
  u16* Tbf    = (u16*)alloc((size_t)NBATCH * NV * NE * 2);
  u16* Ttbf   = (u16*)alloc((size_t)NBATCH * NE * NV * 2);
  float* dbuf = (float*)alloc((size_t)NBATCH * NE * 4);
  float* cbuf = (float*)alloc((size_t)NBATCH * NE * 4);
  u16* YT     = (u16*)alloc((size_t)NBATCH * NE * 64 * 2);
  float* x1   = (float*)alloc((size_t)NBATCH * NV * HID * 4);
  float* z2   = (float*)alloc((size_t)NBATCH * NE * FE * 4);
  const size_t needA = (size_t)NBATCH * NV * NE * 2;
  const size_t needP = (size_t)NBATCH * NE * NE * 2;
  const bool full = (ws_size >= off + needA + needP + 1024);
  const int nb = full ? NBATCH : 1;
  u16* Asc = (u16*)alloc(full ? needA : (size_t)NV * NE * 2);
  u16* P   = (u16*)alloc(full ? needP : (size_t)NE * NE * 2);

  const dim3 blk(256, 1, 1);
  const size_t cbytes = (size_t)NBATCH * NE * 4;

  k_transpose<<<dim3(NE / 32, NV / 32, NBATCH), blk, 0, stream>>>(T, Tbf, Ttbf);

  // ---------------- Layer 1 (node: Fv -> H) ----------------
  k_rowdot<<<dim3(NE / 4, NBATCH), blk, 0, stream>>>(Z, p1, dbuf, NE, FE);
  for (int b0 = 0; b0 < NBATCH; b0 += nb) {
    k_scale<false><<<dim3((NV * NE) / 2048, nb), blk, 0, stream>>>(T, dbuf, Asc, NE, b0);
    hipMemsetAsync(cbuf, 0, cbytes, stream);
    k_gemm<0><<<dim3(NV / 128, NV / 128, nb), blk, 0, stream>>>(
        Asc, (size_t)NV * NE, NE, Tbf, (size_t)NV * NE, NE,
        NV, NE, NV, 0, adjv, P, (unsigned int*)cbuf, nullptr, nullptr, b0);
    k_smallgemm<false><<<dim3(NV / 64, nb), blk, 0, stream>>>(
        X, (size_t)NV * FV, FV, W1, HID, cbuf, YT, (size_t)NV * HID, NV, b0);
    k_gemm<1><<<dim3(1, NV / 128, nb), blk, 0, stream>>>(
        P, (size_t)NV * NV, NV, YT, (size_t)NV * HID, NV,
        NV, NV, HID, HID, nullptr, nullptr, nullptr, b1, x1, b0);
  }
  // ---------------- Layer 2 (edge: Fe -> Fe) ----------------
  k_rowdot<<<dim3(NV / 4, NBATCH), blk, 0, stream>>>(x1, p2, dbuf, NV, HID);
  for (int b0 = 0; b0 < NBATCH; b0 += nb) {
    k_scale<true><<<dim3((NE * NV) / 2048, nb), blk, 0, stream>>>(Ttbf, dbuf, Asc, NV, b0);
    hipMemsetAsync(cbuf, 0, cbytes, stream);
    k_gemm<0><<<dim3(NE / 128, NE / 128, nb), blk, 0, stream>>>(
        Asc, (size_t)NE * NV, NV, Ttbf, (size_t)NE * NV, NV,
        NE, NV, NE, 0, adje, P, (unsigned int*)cbuf, nullptr, nullptr, b0);
    k_smallgemm<true><<<dim3(NE / 64, nb), blk, 0, stream>>>(
        Z, (size_t)NE * FE, FE, W2, FE, cbuf, YT, (size_t)NE * FE, NE, b0);
    k_gemm<1><<<dim3(1, NE / 128, nb), blk, 0, stream>>>(
        P, (size_t)NE * NE, NE, YT, (size_t)NE * FE, NE,
        NE, NE, FE, FE, nullptr, nullptr, nullptr, b2, z2, b0);
  }
  // ---------------- Layer 3 (node: H -> C) ----------------
  k_rowdot<<<dim3(NE / 4, NBATCH), blk, 0, stream>>>(z2, p3, dbuf, NE, FE);
  for (int b0 = 0; b0 < NBATCH; b0 += nb) {
    k_scale<false><<<dim3((NV * NE) / 2048, nb), blk, 0, stream>>>(T, dbuf, Asc, NE, b0);
    hipMemsetAsync(cbuf, 0, cbytes, stream);
    k_gemm<0><<<dim3(NV / 128, NV / 128, nb), blk, 0, stream>>>(
        Asc, (size_t)NV * NE, NE, Tbf, (size_t)NV * NE, NE,
        NV, NE, NV, 0, adjv, P, (unsigned int*)cbuf, nullptr, nullptr, b0);
    k_smallgemm<false><<<dim3(NV / 64, nb), blk, 0, stream>>>(
        x1, (size_t)NV * HID, HID, W3, NCLS, cbuf, YT, (size_t)NV * NCLS, NV, b0);
    k_gemm<2><<<dim3(1, NV / 128, nb), blk, 0, stream>>>(
        P, (size_t)NV * NV, NV, YT, (size_t)NV * NCLS, NV,
        NV, NV, NCLS, NCLS, nullptr, nullptr, nullptr, b3, out, b0);
  }
}

// Round 4
// 759.124 us; speedup vs baseline: 3.1635x; 1.2926x over previous
//
#include <hip/hip_runtime.h>
#include <hip/hip_bf16.h>
#include <stdint.h>

#define DEVI __device__ __forceinline__

typedef __bf16 bf16x8_t __attribute__((ext_vector_type(8)));
typedef float f32x4_t __attribute__((ext_vector_type(4)));
typedef unsigned short u16;

static constexpr int NBATCH = 16;
static constexpr int NV = 1024;
static constexpr int NE = 2048;
static constexpr int FV = 128;
static constexpr int FE = 64;
static constexpr int HID = 128;
static constexpr int NCLS = 16;

DEVI u16 f2bf(float f) { __hip_bfloat16 h = __float2bfloat16(f); return *reinterpret_cast<u16*>(&h); }
DEVI float bf2f(u16 u) { union { unsigned int i; float f; } x; x.i = ((unsigned int)u) << 16; return x.f; }

DEVI void gload_lds16(const void* g, void* l) {
  __builtin_amdgcn_global_load_lds(
      (const __attribute__((address_space(1))) unsigned int*)g,
      (__attribute__((address_space(3))) unsigned int*)l, 16, 0, 0);
}

// ---- K0: T (f32) -> T_bf (bf16, same layout) + Tt_bf (bf16, transposed) ----
__global__ void k_transpose(const float* __restrict__ T, u16* __restrict__ Tbf,
                            u16* __restrict__ Ttbf) {
  __shared__ u16 s[32][33];
  const int b = blockIdx.z;
  const int e0 = blockIdx.x * 32, v0 = blockIdx.y * 32;
  const float* Tb = T + (size_t)b * NV * NE;
  u16* T1 = Tbf + (size_t)b * NV * NE;
  u16* T2 = Ttbf + (size_t)b * NE * NV;
  const int tx = threadIdx.x & 31, ty = threadIdx.x >> 5;
  #pragma unroll
  for (int i = 0; i < 4; ++i) {
    int v = v0 + ty + i * 8;
    u16 u = f2bf(Tb[(size_t)v * NE + e0 + tx]);
    T1[(size_t)v * NE + e0 + tx] = u;
    s[ty + i * 8][tx] = u;
  }
  __syncthreads();
  #pragma unroll
  for (int i = 0; i < 4; ++i) {
    int e = e0 + ty + i * 8;
    T2[(size_t)e * NV + v0 + tx] = s[tx][ty + i * 8];
  }
}

// ---- K1: d[b,r] = sum_c In[b,r,c] * p[c] ---- (one wave per row)
__global__ void k_rowdot(const float* __restrict__ In, const float* __restrict__ p,
                         float* __restrict__ d, int R, int C) {
  const int b = blockIdx.y;
  const int w = threadIdx.x >> 6, l = threadIdx.x & 63;
  const int r = blockIdx.x * 4 + w;
  const float* row = In + ((size_t)b * R + r) * C;
  float s = 0.f;
  for (int c = l; c < C; c += 64) s += row[c] * p[c];
  #pragma unroll
  for (int o = 32; o; o >>= 1) s += __shfl_xor(s, o);
  if (l == 0) d[(size_t)b * R + r] = s;
}

// ---- K2: Asc[bi, r, k] = In[bg, r, k] * d[bg, k]  (bf16 out) ----
template <bool BFIN>
__global__ void k_scale(const void* __restrict__ In, const float* __restrict__ d,
                        u16* __restrict__ Out, int K, int b0) {
  const int bi = blockIdx.y, bg = b0 + bi;
  const size_t elems = (size_t)NV * NE;
  const size_t idx = ((size_t)blockIdx.x * 256 + threadIdx.x) * 8;
  const float* dd = d + (size_t)bg * K;
  const int k = (int)(idx & (size_t)(K - 1));
  float f[8];
  if (BFIN) {
    const u16* in = (const u16*)In + (size_t)bg * elems + idx;
    uint4 raw = *(const uint4*)in;
    f[0] = bf2f(raw.x & 0xffff); f[1] = bf2f(raw.x >> 16);
    f[2] = bf2f(raw.y & 0xffff); f[3] = bf2f(raw.y >> 16);
    f[4] = bf2f(raw.z & 0xffff); f[5] = bf2f(raw.z >> 16);
    f[6] = bf2f(raw.w & 0xffff); f[7] = bf2f(raw.w >> 16);
  } else {
    const float* in = (const float*)In + (size_t)bg * elems + idx;
    float4 a0 = *(const float4*)in, a1 = *(const float4*)(in + 4);
    f[0] = a0.x; f[1] = a0.y; f[2] = a0.z; f[3] = a0.w;
    f[4] = a1.x; f[5] = a1.y; f[6] = a1.z; f[7] = a1.w;
  }
  u16 o[8];
  #pragma unroll
  for (int t = 0; t < 8; ++t) o[t] = f2bf(f[t] * dd[k + t]);
  *(uint4*)((u16*)Out + (size_t)bi * elems + idx) = *(uint4*)o;
}

// ---- K3: 256x256-tile GEMM  P[bi] = (diag?1:A*B^T) * adj[bg]  (bf16 out) ----
// A: (M x K) bf16 row-major; B: (M x K) bf16 row-major (output col j = B row j).
// 512 threads = 8 waves (2 M x 4 N), per-wave 128x64 output, BK=64,
// double-buffered 128 KiB LDS, stage-early global_load_lds (T14/T3),
// one barrier per K-tile, T2 XOR-swizzle (byte ^= ((row&7)<<4)) via
// inverse-swizzled global source + swizzled ds_read, setprio around MFMA.
__global__ __launch_bounds__(512, 2) void k_gemm256(
    const u16* __restrict__ A, size_t sA, int ldA,
    const u16* __restrict__ Bm, size_t sB, int ldB,
    int M, int K,
    const float* __restrict__ adj, u16* __restrict__ Pout, int b0) {
  extern __shared__ char smem[];
  // ---- bijective XCD swizzle of flattened block index ----
  const int gx = gridDim.x, gy = gridDim.y;
  const int total = gx * gy * gridDim.z;
  int orig = blockIdx.x + gx * (blockIdx.y + gy * blockIdx.z);
  const int cpx = total >> 3;                 // total is a multiple of 8
  int swz = (orig & 7) * cpx + (orig >> 3);
  const int bx = swz % gx;
  const int by = (swz / gx) % gy;
  const int bi = swz / (gx * gy);
  const int bg = b0 + bi;

  const u16* Ab = A + (size_t)bi * sA;
  const u16* Bb = Bm + (size_t)bg * sB;
  const int tm = by * 256, tn = bx * 256;
  const int tid = threadIdx.x, wid = tid >> 6, l = tid & 63;
  const int wr = wid >> 2, wc = wid & 3;

  // staging addresses: dest byte (linear) = ld*8192 + tid*16; source is
  // inverse-swizzled: row = ld*64 + (tid>>3), col = 8*((tid&7) ^ ((tid>>3)&7))
  const int srow = tid >> 3;
  const int scol = (((tid & 7) ^ (srow & 7)) << 3);

  // fragment read offsets (bytes), swizzled: row-part + (col-part ^ ((l&7)<<4))
  const int Lx = (l & 7) << 4;
  const int colb0 = (((l >> 4) << 4)) ^ Lx;          // kk = 0
  const int colb1 = (64 + ((l >> 4) << 4)) ^ Lx;     // kk = 1
  const int arowb = (wr * 128 + (l & 15)) * 128;     // + m*2048
  const int browb = (wc * 64 + (l & 15)) * 128;      // + n*2048

  auto stage = [&](int buf, int k0) {
    char* ab = smem + (buf << 16);
    char* bb = ab + 32768;
    #pragma unroll
    for (int ld2 = 0; ld2 < 4; ++ld2) {
      gload_lds16(Ab + (size_t)(tm + ld2 * 64 + srow) * ldA + (k0 + scol),
                  ab + ld2 * 8192 + tid * 16);
      gload_lds16(Bb + (size_t)(tn + ld2 * 64 + srow) * ldB + (k0 + scol),
                  bb + ld2 * 8192 + tid * 16);
    }
  };

  f32x4_t acc[8][4];
  const f32x4_t zv = {0.f, 0.f, 0.f, 0.f};
  #pragma unroll
  for (int m = 0; m < 8; ++m)
    #pragma unroll
    for (int n = 0; n < 4; ++n) acc[m][n] = zv;

  const int NT = K >> 6;
  stage(0, 0);
  __syncthreads();

  for (int kt = 0; kt < NT; ++kt) {
    const int buf = kt & 1;
    if (kt + 1 < NT) stage(buf ^ 1, (kt + 1) << 6);  // issue-early prefetch
    char* abase = smem + (buf << 16);
    char* bbase = abase + 32768;
    bf16x8_t af[4][2], bfr[4][2];
    // ---- PH1: A-low (m0..3) + B-low (n0..1) -> quad (lo,lo) ----
    #pragma unroll
    for (int m = 0; m < 4; ++m) {
      af[m][0] = *(const bf16x8_t*)(abase + arowb + m * 2048 + colb0);
      af[m][1] = *(const bf16x8_t*)(abase + arowb + m * 2048 + colb1);
    }
    #pragma unroll
    for (int n = 0; n < 2; ++n) {
      bfr[n][0] = *(const bf16x8_t*)(bbase + browb + n * 2048 + colb0);
      bfr[n][1] = *(const bf16x8_t*)(bbase + browb + n * 2048 + colb1);
    }
    __builtin_amdgcn_s_setprio(1);
    #pragma unroll
    for (int m = 0; m < 4; ++m)
      #pragma unroll
      for (int n = 0; n < 2; ++n)
        #pragma unroll
        for (int kk = 0; kk < 2; ++kk)
          acc[m][n] = __builtin_amdgcn_mfma_f32_16x16x32_bf16(af[m][kk], bfr[n][kk], acc[m][n], 0, 0, 0);
    __builtin_amdgcn_s_setprio(0);
    // ---- PH2: B-high (n2..3) -> quad (lo,hi) ----
    #pragma unroll
    for (int n = 2; n < 4; ++n) {
      bfr[n][0] = *(const bf16x8_t*)(bbase + browb + n * 2048 + colb0);
      bfr[n][1] = *(const bf16x8_t*)(bbase + browb + n * 2048 + colb1);
    }
    __builtin_amdgcn_s_setprio(1);
    #pragma unroll
    for (int m = 0; m < 4; ++m)
      #pragma unroll
      for (int n = 2; n < 4; ++n)
        #pragma unroll
        for (int kk = 0; kk < 2; ++kk)
          acc[m][n] = __builtin_amdgcn_mfma_f32_16x16x32_bf16(af[m][kk], bfr[n][kk], acc[m][n], 0, 0, 0);
    __builtin_amdgcn_s_setprio(0);
    // ---- PH3: A-high (m4..7) -> quad (hi,hi) ----
    #pragma unroll
    for (int m = 0; m < 4; ++m) {
      af[m][0] = *(const bf16x8_t*)(abase + arowb + (m + 4) * 2048 + colb0);
      af[m][1] = *(const bf16x8_t*)(abase + arowb + (m + 4) * 2048 + colb1);
    }
    __builtin_amdgcn_s_setprio(1);
    #pragma unroll
    for (int m = 0; m < 4; ++m)
      #pragma unroll
      for (int n = 2; n < 4; ++n)
        #pragma unroll
        for (int kk = 0; kk < 2; ++kk)
          acc[m + 4][n] = __builtin_amdgcn_mfma_f32_16x16x32_bf16(af[m][kk], bfr[n][kk], acc[m + 4][n], 0, 0, 0);
    __builtin_amdgcn_s_setprio(0);
    // ---- PH4: quad (hi,lo), B-low still live ----
    __builtin_amdgcn_s_setprio(1);
    #pragma unroll
    for (int m = 0; m < 4; ++m)
      #pragma unroll
      for (int n = 0; n < 2; ++n)
        #pragma unroll
        for (int kk = 0; kk < 2; ++kk)
          acc[m + 4][n] = __builtin_amdgcn_mfma_f32_16x16x32_bf16(af[m][kk], bfr[n][kk], acc[m + 4][n], 0, 0, 0);
    __builtin_amdgcn_s_setprio(0);
    __syncthreads();  // drains prefetch vmcnt + everyone done reading buf
  }

  // ---- epilogue: diag=1, * adj, bf16 store ----
  const float* adjb = adj + (size_t)bg * M * M;
  u16* Pb = Pout + (size_t)bi * (size_t)M * M;
  #pragma unroll
  for (int m = 0; m < 8; ++m)
    #pragma unroll
    for (int n = 0; n < 4; ++n)
      #pragma unroll
      for (int q = 0; q < 4; ++q) {
        int row = tm + wr * 128 + m * 16 + (l >> 4) * 4 + q;
        int col = tn + wc * 64 + n * 16 + (l & 15);
        float v = acc[m][n][q];
        if (row == col) v = 1.0f;
        v *= adjb[(size_t)row * M + col];
        Pb[(size_t)row * M + col] = f2bf(v);
      }
}

// ---- K6: 128-tile GEMM for the skinny P@Y products (EPI 1: relu+bias f32,
//          EPI 2: bias f32). A MxK bf16, B = N-rows x K bf16. ----
template <int EPI>
__global__ __launch_bounds__(256) void k_gemm(
    const u16* __restrict__ A, size_t sA, int ldA,
    const u16* __restrict__ Bm, size_t sB, int ldB,
    int M, int K, int Nrows, int Ncols,
    const float* __restrict__ bias, float* __restrict__ Fout, int b0) {
  __shared__ __align__(16) u16 As[2][128 * 32];
  __shared__ __align__(16) u16 Bs[2][128 * 32];
  const int bi = blockIdx.z, bg = b0 + bi;
  const u16* Ab = A + (size_t)bi * sA;
  const u16* Bb = Bm + (size_t)bg * sB;
  const int tm = blockIdx.y * 128, tn = blockIdx.x * 128;
  const int tid = threadIdx.x, w = tid >> 6, l = tid & 63;
  const int wm = (w >> 1) * 64, wn = (w & 1) * 64;
  const int lr = l & 15, kg = (l >> 4) * 8;
  const int chunk = l & 3;
  int arow[2], brow[2];
  #pragma unroll
  for (int i = 0; i < 2; ++i) {
    int r = (i * 4 + w) * 16 + (l >> 2);
    arow[i] = tm + r;
    int rb = tn + r;
    brow[i] = rb < Nrows ? rb : Nrows - 1;
  }
  f32x4_t acc[4][4];
  const f32x4_t zv = {0.f, 0.f, 0.f, 0.f};
  #pragma unroll
  for (int m = 0; m < 4; ++m)
    #pragma unroll
    for (int n = 0; n < 4; ++n) acc[m][n] = zv;

  auto stage = [&](int buf, int k0) {
    #pragma unroll
    for (int i = 0; i < 2; ++i) {
      gload_lds16(Ab + (size_t)arow[i] * ldA + k0 + chunk * 8,
                  (char*)As[buf] + (i * 4 + w) * 1024);
      gload_lds16(Bb + (size_t)brow[i] * ldB + k0 + chunk * 8,
                  (char*)Bs[buf] + (i * 4 + w) * 1024);
    }
  };

  const int nsteps = K >> 5;
  stage(0, 0);
  __syncthreads();
  for (int s = 0; s < nsteps; ++s) {
    const int cur = s & 1;
    if (s + 1 < nsteps) stage(cur ^ 1, (s + 1) << 5);
    bf16x8_t af[4], bfr[4];
    #pragma unroll
    for (int m = 0; m < 4; ++m) af[m] = *(const bf16x8_t*)&As[cur][(wm + m * 16 + lr) * 32 + kg];
    #pragma unroll
    for (int n = 0; n < 4; ++n) bfr[n] = *(const bf16x8_t*)&Bs[cur][(wn + n * 16 + lr) * 32 + kg];
    #pragma unroll
    for (int m = 0; m < 4; ++m)
      #pragma unroll
      for (int n = 0; n < 4; ++n)
        acc[m][n] = __builtin_amdgcn_mfma_f32_16x16x32_bf16(af[m], bfr[n], acc[m][n], 0, 0, 0);
    __syncthreads();
  }

  float* Ob = Fout + (size_t)bg * M * Ncols;
  #pragma unroll
  for (int m = 0; m < 4; ++m)
    #pragma unroll
    for (int n = 0; n < 4; ++n)
      #pragma unroll
      for (int q = 0; q < 4; ++q) {
        int row = tm + wm + m * 16 + (l >> 4) * 4 + q;
        int col = tn + wn + n * 16 + lr;
        if (col < Ncols) {
          float v = acc[m][n][q] + bias[col];
          if (EPI == 1) v = fmaxf(v, 0.f);
          Ob[(size_t)row * Ncols + col] = v;
        }
      }
}

// ---- K4: c[bg, j] = max_i P[bi, i, j]  (row-sliced, atomicMax on float bits) ----
// True col max is > 0 (diagonal = adj > 0), so clamping partials at 0 and
// uint atomicMax on float bit patterns is exact.
__global__ void k_colmax(const u16* __restrict__ P, unsigned int* __restrict__ c,
                         int M, int N, int rowsPer, int b0) {
  const int bi = blockIdx.z, bg = b0 + bi;
  const u16* Pb = P + (size_t)bi * (size_t)M * N;
  const int j = (blockIdx.x * 256 + threadIdx.x) * 4;
  const int r0 = blockIdx.y * rowsPer;
  float m0 = 0.f, m1 = 0.f, m2 = 0.f, m3 = 0.f;
  for (int i = r0; i < r0 + rowsPer; ++i) {
    uint2 v = *(const uint2*)(Pb + (size_t)i * N + j);
    m0 = fmaxf(m0, bf2f(v.x & 0xffff)); m1 = fmaxf(m1, bf2f(v.x >> 16));
    m2 = fmaxf(m2, bf2f(v.y & 0xffff)); m3 = fmaxf(m3, bf2f(v.y >> 16));
  }
  unsigned int* cb = c + (size_t)bg * N;
  atomicMax(cb + j + 0, __float_as_uint(m0));
  atomicMax(cb + j + 1, __float_as_uint(m1));
  atomicMax(cb + j + 2, __float_as_uint(m2));
  atomicMax(cb + j + 3, __float_as_uint(m3));
}

// ---- K5: YT[bg, c, j] = bf16( (sum_k Xin[bg,j,k] W[k,c]) / cmax[bg,j] ) ----
template <bool RELU_IN>
__global__ __launch_bounds__(256) void k_smallgemm(
    const float* __restrict__ X, size_t sX, int Kd,
    const float* __restrict__ W, int Cc,
    const float* __restrict__ cmax, u16* __restrict__ YT, size_t sY,
    int Nj, int b0) {
  __shared__ float Xs[64][129];
  __shared__ float Ws[128][33];
  const int bg = b0 + blockIdx.y;
  const float* Xb = X + (size_t)bg * sX;
  const int j0 = blockIdx.x * 64;
  const int tid = threadIdx.x;
  for (int idx = tid; idx < 64 * (Kd / 4); idx += 256) {
    int r = idx / (Kd / 4), q = idx % (Kd / 4);
    float4 v = *(const float4*)(Xb + (size_t)(j0 + r) * Kd + q * 4);
    if (RELU_IN) {
      v.x = fmaxf(v.x, 0.f); v.y = fmaxf(v.y, 0.f);
      v.z = fmaxf(v.z, 0.f); v.w = fmaxf(v.w, 0.f);
    }
    Xs[r][q * 4 + 0] = v.x; Xs[r][q * 4 + 1] = v.y;
    Xs[r][q * 4 + 2] = v.z; Xs[r][q * 4 + 3] = v.w;
  }
  const int r = tid & 63, cg = tid >> 6;
  const float rinv = 1.0f / cmax[(size_t)bg * Nj + j0 + r];
  for (int c0 = 0; c0 < Cc; c0 += 32) {
    __syncthreads();
    for (int idx = tid; idx < Kd * 32; idx += 256) {
      int k = idx >> 5, c = c0 + (idx & 31);
      Ws[k][idx & 31] = (c < Cc) ? W[(size_t)k * Cc + c] : 0.f;
    }
    __syncthreads();
    float acc[8] = {0.f, 0.f, 0.f, 0.f, 0.f, 0.f, 0.f, 0.f};
    for (int k = 0; k < Kd; ++k) {
      float xv = Xs[r][k];
      #pragma unroll
      for (int cc = 0; cc < 8; ++cc) acc[cc] += xv * Ws[k][cg * 8 + cc];
    }
    #pragma unroll
    for (int cc = 0; cc < 8; ++cc) {
      int c = c0 + cg * 8 + cc;
      if (c < Cc) YT[(size_t)bg * sY + (size_t)c * Nj + j0 + r] = f2bf(acc[cc] * rinv);
    }
  }
}

extern "C" void kernel_launch(void* const* d_in, const int* in_sizes, int n_in,
                              void* d_out, int out_size, void* d_ws, size_t ws_size,
                              hipStream_t stream) {
  const float* X    = (const float*)d_in[0];
  const float* Z    = (const float*)d_in[1];
  const float* adje = (const float*)d_in[2];
  const float* adjv = (const float*)d_in[3];
  const float* T    = (const float*)d_in[4];
  const float* W1   = (const float*)d_in[5];
  const float* b1   = (const float*)d_in[6];
  const float* p1   = (const float*)d_in[7];
  const float* W2   = (const float*)d_in[8];
  const float* b2   = (const float*)d_in[9];
  const float* p2   = (const float*)d_in[10];
  const float* W3   = (const float*)d_in[11];
  const float* b3   = (const float*)d_in[12];
  const float* p3   = (const float*)d_in[13];
  float* out = (float*)d_out;
  (void)in_sizes; (void)n_in; (void)out_size;

  hipFuncSetAttribute(reinterpret_cast<const void*>(k_gemm256),
                      hipFuncAttributeMaxDynamicSharedMemorySize, 131072);

  char* ws = (char*)d_ws;
  size_t off = 0;
  auto alloc = [&](size_t n) -> char* {
    char* p = ws + off; off = (off + n + 255) & ~(size_t)255; return p;
  };
  u16* Tbf    = (u16*)alloc((size_t)NBATCH * NV * NE * 2);
  u16* Ttbf   = (u16*)alloc((size_t)NBATCH * NE * NV * 2);
  float* dbuf = (float*)alloc((size_t)NBATCH * NE * 4);
  float* cbuf = (float*)alloc((size_t)NBATCH * NE * 4);
  u16* YT     = (u16*)alloc((size_t)NBATCH * NE * 64 * 2);
  float* x1   = (float*)alloc((size_t)NBATCH * NV * HID * 4);
  float* z2   = (float*)alloc((size_t)NBATCH * NE * FE * 4);
  const size_t needA = (size_t)NBATCH * NV * NE * 2;
  const size_t needP = (size_t)NBATCH * NE * NE * 2;
  const bool full = (ws_size >= off + needA + needP + 1024);
  const int nb = full ? NBATCH : 1;
  u16* Asc = (u16*)alloc(full ? needA : (size_t)NV * NE * 2);
  u16* P   = (u16*)alloc(full ? needP : (size_t)NE * NE * 2);

  const dim3 blk(256, 1, 1);
  const dim3 blk512(512, 1, 1);
  const size_t cbytes = (size_t)NBATCH * NE * 4;

  k_transpose<<<dim3(NE / 32, NV / 32, NBATCH), blk, 0, stream>>>(T, Tbf, Ttbf);

  // ---------------- Layer 1 (node: Fv -> H) ----------------
  k_rowdot<<<dim3(NE / 4, NBATCH), blk, 0, stream>>>(Z, p1, dbuf, NE, FE);
  for (int b0 = 0; b0 < NBATCH; b0 += nb) {
    k_scale<false><<<dim3((NV * NE) / 2048, nb), blk, 0, stream>>>(T, dbuf, Asc, NE, b0);
    k_gemm256<<<dim3(NV / 256, NV / 256, nb), blk512, 131072, stream>>>(
        Asc, (size_t)NV * NE, NE, Tbf, (size_t)NV * NE, NE, NV, NE, adjv, P, b0);
    hipMemsetAsync(cbuf, 0, cbytes, stream);
    k_colmax<<<dim3(NV / 1024, NV / 32, nb), blk, 0, stream>>>(
        P, (unsigned int*)cbuf, NV, NV, 32, b0);
    k_smallgemm<false><<<dim3(NV / 64, nb), blk, 0, stream>>>(
        X, (size_t)NV * FV, FV, W1, HID, cbuf, YT, (size_t)NV * HID, NV, b0);
    k_gemm<1><<<dim3(1, NV / 128, nb), blk, 0, stream>>>(
        P, (size_t)NV * NV, NV, YT, (size_t)NV * HID, NV,
        NV, NV, HID, HID, b1, x1, b0);
  }
  // ---------------- Layer 2 (edge: Fe -> Fe) ----------------
  k_rowdot<<<dim3(NV / 4, NBATCH), blk, 0, stream>>>(x1, p2, dbuf, NV, HID);
  for (int b0 = 0; b0 < NBATCH; b0 += nb) {
    k_scale<true><<<dim3((NE * NV) / 2048, nb), blk, 0, stream>>>(Ttbf, dbuf, Asc, NV, b0);
    k_gemm256<<<dim3(NE / 256, NE / 256, nb), blk512, 131072, stream>>>(
        Asc, (size_t)NE * NV, NV, Ttbf, (size_t)NE * NV, NV, NE, NV, adje, P, b0);
    hipMemsetAsync(cbuf, 0, cbytes, stream);
    k_colmax<<<dim3(NE / 1024, NE / 64, nb), blk, 0, stream>>>(
        P, (unsigned int*)cbuf, NE, NE, 64, b0);
    k_smallgemm<true><<<dim3(NE / 64, nb), blk, 0, stream>>>(
        Z, (size_t)NE * FE, FE, W2, FE, cbuf, YT, (size_t)NE * FE, NE, b0);
    k_gemm<1><<<dim3(1, NE / 128, nb), blk, 0, stream>>>(
        P, (size_t)NE * NE, NE, YT, (size_t)NE * FE, NE,
        NE, NE, FE, FE, b2, z2, b0);
  }
  // ---------------- Layer 3 (node: H -> C) ----------------
  k_rowdot<<<dim3(NE / 4, NBATCH), blk, 0, stream>>>(z2, p3, dbuf, NE, FE);
  for (int b0 = 0; b0 < NBATCH; b0 += nb) {
    k_scale<false><<<dim3((NV * NE) / 2048, nb), blk, 0, stream>>>(T, dbuf, Asc, NE, b0);
    k_gemm256<<<dim3(NV / 256, NV / 256, nb), blk512, 131072, stream>>>(
        Asc, (size_t)NV * NE, NE, Tbf, (size_t)NV * NE, NE, NV, NE, adjv, P, b0);
    hipMemsetAsync(cbuf, 0, cbytes, stream);
    k_colmax<<<dim3(NV / 1024, NV / 32, nb), blk, 0, stream>>>(
        P, (unsigned int*)cbuf, NV, NV, 32, b0);
    k_smallgemm<false><<<dim3(NV / 64, nb), blk, 0, stream>>>(
        x1, (size_t)NV * HID, HID, W3, NCLS, cbuf, YT, (size_t)NV * NCLS, NV, b0);
    k_gemm<2><<<dim3(1, NV / 128, nb), blk, 0, stream>>>(
        P, (size_t)NV * NV, NV, YT, (size_t)NV * NCLS, NV,
        NV, NV, NCLS, NCLS, b3, out, b0);
  }
}

// Round 5
// 734.927 us; speedup vs baseline: 3.2677x; 1.0329x over previous
//
#include <hip/hip_runtime.h>
#include <hip/hip_bf16.h>
#include <stdint.h>

#define DEVI __device__ __forceinline__

typedef __bf16 bf16x8_t __attribute__((ext_vector_type(8)));
typedef float f32x4_t __attribute__((ext_vector_type(4)));
typedef unsigned short u16;

static constexpr int NBATCH = 16;
static constexpr int NV = 1024;
static constexpr int NE = 2048;
static constexpr int FV = 128;
static constexpr int FE = 64;
static constexpr int HID = 128;
static constexpr int NCLS = 16;

DEVI u16 f2bf(float f) { __hip_bfloat16 h = __float2bfloat16(f); return *reinterpret_cast<u16*>(&h); }
DEVI float bf2f(u16 u) { union { unsigned int i; float f; } x; x.i = ((unsigned int)u) << 16; return x.f; }

DEVI void gload_lds16(const void* g, void* l) {
  __builtin_amdgcn_global_load_lds(
      (const __attribute__((address_space(1))) unsigned int*)g,
      (__attribute__((address_space(3))) unsigned int*)l, 16, 0, 0);
}

// ---- K0: T (f32) -> T_bf (bf16, same layout) + Tt_bf (bf16, transposed) ----
__global__ void k_transpose(const float* __restrict__ T, u16* __restrict__ Tbf,
                            u16* __restrict__ Ttbf) {
  __shared__ u16 s[32][33];
  const int b = blockIdx.z;
  const int e0 = blockIdx.x * 32, v0 = blockIdx.y * 32;
  const float* Tb = T + (size_t)b * NV * NE;
  u16* T1 = Tbf + (size_t)b * NV * NE;
  u16* T2 = Ttbf + (size_t)b * NE * NV;
  const int tx = threadIdx.x & 31, ty = threadIdx.x >> 5;
  #pragma unroll
  for (int i = 0; i < 4; ++i) {
    int v = v0 + ty + i * 8;
    u16 u = f2bf(Tb[(size_t)v * NE + e0 + tx]);
    T1[(size_t)v * NE + e0 + tx] = u;
    s[ty + i * 8][tx] = u;
  }
  __syncthreads();
  #pragma unroll
  for (int i = 0; i < 4; ++i) {
    int e = e0 + ty + i * 8;
    T2[(size_t)e * NV + v0 + tx] = s[tx][ty + i * 8];
  }
}

// ---- K1: d[b,r] = sum_c In[b,r,c] * p[c] ---- (one wave per row)
__global__ void k_rowdot(const float* __restrict__ In, const float* __restrict__ p,
                         float* __restrict__ d, int R, int C) {
  const int b = blockIdx.y;
  const int w = threadIdx.x >> 6, l = threadIdx.x & 63;
  const int r = blockIdx.x * 4 + w;
  const float* row = In + ((size_t)b * R + r) * C;
  float s = 0.f;
  for (int c = l; c < C; c += 64) s += row[c] * p[c];
  #pragma unroll
  for (int o = 32; o; o >>= 1) s += __shfl_xor(s, o);
  if (l == 0) d[(size_t)b * R + r] = s;
}

// ---- K2: Asc[bi, r, k] = In[bg, r, k] * d[bg, k]  (bf16 out) ----
template <bool BFIN>
__global__ void k_scale(const void* __restrict__ In, const float* __restrict__ d,
                        u16* __restrict__ Out, int K, int b0) {
  const int bi = blockIdx.y, bg = b0 + bi;
  const size_t elems = (size_t)NV * NE;
  const size_t idx = ((size_t)blockIdx.x * 256 + threadIdx.x) * 8;
  const float* dd = d + (size_t)bg * K;
  const int k = (int)(idx & (size_t)(K - 1));
  float f[8];
  if (BFIN) {
    const u16* in = (const u16*)In + (size_t)bg * elems + idx;
    uint4 raw = *(const uint4*)in;
    f[0] = bf2f(raw.x & 0xffff); f[1] = bf2f(raw.x >> 16);
    f[2] = bf2f(raw.y & 0xffff); f[3] = bf2f(raw.y >> 16);
    f[4] = bf2f(raw.z & 0xffff); f[5] = bf2f(raw.z >> 16);
    f[6] = bf2f(raw.w & 0xffff); f[7] = bf2f(raw.w >> 16);
  } else {
    const float* in = (const float*)In + (size_t)bg * elems + idx;
    float4 a0 = *(const float4*)in, a1 = *(const float4*)(in + 4);
    f[0] = a0.x; f[1] = a0.y; f[2] = a0.z; f[3] = a0.w;
    f[4] = a1.x; f[5] = a1.y; f[6] = a1.z; f[7] = a1.w;
  }
  u16 o[8];
  #pragma unroll
  for (int t = 0; t < 8; ++t) o[t] = f2bf(f[t] * dd[k + t]);
  *(uint4*)((u16*)Out + (size_t)bi * elems + idx) = *(uint4*)o;
}

// ================= K3: 256x256-tile 8-phase GEMM =================
// P[bi] = (diag?1:A*B^T) * adj[bg]  (bf16 out).  A,B: bf16 row-major (ld = K).
// 512 thr = 8 waves (2M x 4N), per-wave 128x64, BK=64, 2 LDS bufs (128 KiB).
// Per K-tile: 4 quadrant phases; each stages one 16 KiB part of tile kt+1
// (linear dest, permuted row order so parts are contiguous), raw s_barrier +
// counted vmcnt(4) (never 0 in main loop), lgkmcnt(0)+sched_barrier before
// setprio-wrapped MFMA cluster. T2 XOR swizzle via inverse-swizzled source.
// Part order: s1=PA1(A rows {0-63,128-191}), s2=PB1(B rows nh0),
// s3=PB2(B rows nh1), s4=PA2(A rows {64-127,192-255}).
// Quadrants: ph1(0,0) ph2(0,1) ph3(1,0) ph4(1,1); stage->consume gap >= 3.
#define LDA8(MH) \
  _Pragma("unroll") \
  for (int m = 0; m < 4; ++m) { \
    const char* pA = abase + ((MH) * 128 + wr * 64 + m * 16 + lr) * 128; \
    af[m][0] = *(const bf16x8_t*)(pA + colb0); \
    af[m][1] = *(const bf16x8_t*)(pA + colb1); \
  }
#define LDB4(BF, NH) \
  _Pragma("unroll") \
  for (int n = 0; n < 2; ++n) { \
    const char* pB = bbase + ((NH) * 128 + wc * 32 + n * 16 + lr) * 128; \
    BF[n][0] = *(const bf16x8_t*)(pB + colb0); \
    BF[n][1] = *(const bf16x8_t*)(pB + colb1); \
  }
#define MFMA_QUAD(MH, NH, BF) \
  __builtin_amdgcn_s_setprio(1); \
  _Pragma("unroll") \
  for (int m = 0; m < 4; ++m) \
    _Pragma("unroll") \
    for (int n = 0; n < 2; ++n) \
      _Pragma("unroll") \
      for (int kk = 0; kk < 2; ++kk) \
        acc[(MH) * 4 + m][(NH) * 2 + n] = __builtin_amdgcn_mfma_f32_16x16x32_bf16( \
            af[m][kk], BF[n][kk], acc[(MH) * 4 + m][(NH) * 2 + n], 0, 0, 0); \
  __builtin_amdgcn_s_setprio(0);

__global__ __launch_bounds__(512, 2) void k_gemm256(
    const u16* __restrict__ A, size_t sA, int ldA,
    const u16* __restrict__ Bm, size_t sB, int ldB,
    int M, int K,
    const float* __restrict__ adj, u16* __restrict__ Pout, int b0) {
  extern __shared__ __align__(16) char smem[];
  // bijective XCD swizzle (grid size is a multiple of 8)
  const int gx = gridDim.x, gy = gridDim.y;
  const int total = gx * gy * gridDim.z;
  int orig = blockIdx.x + gx * (blockIdx.y + gy * blockIdx.z);
  const int cpx = total >> 3;
  int swz = (orig & 7) * cpx + (orig >> 3);
  const int bx = swz % gx;
  const int by = (swz / gx) % gy;
  const int bi = swz / (gx * gy);
  const int bg = b0 + bi;

  const u16* Ab = A + (size_t)bi * sA;
  const u16* Bb = Bm + (size_t)bg * sB;
  const int tm = by * 256, tn = bx * 256;
  const int tid = threadIdx.x, wid = tid >> 6, l = tid & 63;
  const int wr = wid >> 2, wc = wid & 3;
  const int lr = l & 15;
  const int Lx = (l & 7) << 4;
  const int colb0 = (((l >> 4) << 4)) ^ Lx;
  const int colb1 = (64 + ((l >> 4) << 4)) ^ Lx;
  const int srow = tid >> 3;
  const int scol = (((tid & 7) ^ (srow & 7)) << 3);

  // LDS row permutations: A rho -> global row {g=rho>>7, wr=(rho>>6)&1, j=rho&63}
  //                       B rho -> {g=rho>>7, wc=(rho>>5)&3, j=rho&31}
  auto stageA = [&](char* ab, int k0, int pa) {
    const int rho = pa * 64 + srow;
    const int row = ((rho >> 6) & 1) * 128 + (rho >> 7) * 64 + (rho & 63);
    gload_lds16(Ab + (size_t)(tm + row) * ldA + (k0 + scol), ab + pa * 8192 + tid * 16);
  };
  auto stageB = [&](char* bb, int k0, int pb) {
    const int rho = pb * 64 + srow;
    const int row = ((rho >> 5) & 3) * 64 + (rho >> 7) * 32 + (rho & 31);
    gload_lds16(Bb + (size_t)(tn + row) * ldB + (k0 + scol), bb + pb * 8192 + tid * 16);
  };

  f32x4_t acc[8][4];
  const f32x4_t zv = {0.f, 0.f, 0.f, 0.f};
  #pragma unroll
  for (int m = 0; m < 8; ++m)
    #pragma unroll
    for (int n = 0; n < 4; ++n) acc[m][n] = zv;
  bf16x8_t af[4][2], blo[2][2], bhi[2][2];

  const int NT = K >> 6;
  // prologue: stage tile 0 parts s1..s4 (issue order defines vmcnt ledger)
  {
    char* ab = smem; char* bb = smem + 32768;
    stageA(ab, 0, 0); stageA(ab, 0, 1);   // s1 PA1
    stageB(bb, 0, 0); stageB(bb, 0, 1);   // s2 PB1
    stageB(bb, 0, 2); stageB(bb, 0, 3);   // s3 PB2
    stageA(ab, 0, 2); stageA(ab, 0, 3);   // s4 PA2
  }
  asm volatile("s_waitcnt vmcnt(4)" ::: "memory");  // s1,s2 landed
  __builtin_amdgcn_s_barrier();

  for (int kt = 0; kt < NT; ++kt) {
    char* abase = smem + ((kt & 1) << 16);
    char* bbase = abase + 32768;
    char* nab = smem + (((kt & 1) ^ 1) << 16);
    char* nbb = nab + 32768;
    const int nk0 = (kt + 1) << 6;
    const bool pre = (kt + 1 < NT);

    // ---- PH1: quadrant (0,0) ----
    LDA8(0);
    LDB4(blo, 0);
    if (pre) { stageA(nab, nk0, 0); stageA(nab, nk0, 1); }  // s1'
    __builtin_amdgcn_s_barrier();
    asm volatile("s_waitcnt lgkmcnt(0)" ::: "memory");
    __builtin_amdgcn_sched_barrier(0);
    MFMA_QUAD(0, 0, blo);
    if (pre) asm volatile("s_waitcnt vmcnt(4)" ::: "memory");  // PB2 cur ready
    else     asm volatile("s_waitcnt vmcnt(2)" ::: "memory");
    __builtin_amdgcn_s_barrier();

    // ---- PH2: quadrant (0,1) ----
    LDB4(bhi, 1);
    if (pre) { stageB(nbb, nk0, 0); stageB(nbb, nk0, 1); }  // s2'
    __builtin_amdgcn_s_barrier();
    asm volatile("s_waitcnt lgkmcnt(0)" ::: "memory");
    __builtin_amdgcn_sched_barrier(0);
    MFMA_QUAD(0, 1, bhi);
    if (pre) asm volatile("s_waitcnt vmcnt(4)" ::: "memory");  // PA2 cur ready
    else     asm volatile("s_waitcnt vmcnt(0)" ::: "memory");
    __builtin_amdgcn_s_barrier();

    // ---- PH3: quadrant (1,0) ----
    LDA8(1);
    if (pre) { stageB(nbb, nk0, 2); stageB(nbb, nk0, 3); }  // s3'
    __builtin_amdgcn_s_barrier();
    asm volatile("s_waitcnt lgkmcnt(0)" ::: "memory");
    __builtin_amdgcn_sched_barrier(0);
    MFMA_QUAD(1, 0, blo);
    __builtin_amdgcn_s_barrier();

    // ---- PH4: quadrant (1,1) ----
    if (pre) { stageA(nab, nk0, 2); stageA(nab, nk0, 3); }  // s4'
    __builtin_amdgcn_s_barrier();
    MFMA_QUAD(1, 1, bhi);
    if (pre) asm volatile("s_waitcnt vmcnt(4)" ::: "memory");  // s1',s2' landed
    __builtin_amdgcn_s_barrier();
  }

  // ---- epilogue: diag=1, * adj, bf16 store ----
  const float* adjb = adj + (size_t)bg * M * M;
  u16* Pb = Pout + (size_t)bi * (size_t)M * M;
  #pragma unroll
  for (int m = 0; m < 8; ++m)
    #pragma unroll
    for (int n = 0; n < 4; ++n)
      #pragma unroll
      for (int q = 0; q < 4; ++q) {
        int row = tm + wr * 128 + m * 16 + (l >> 4) * 4 + q;
        int col = tn + wc * 64 + n * 16 + (l & 15);
        float v = acc[m][n][q];
        if (row == col) v = 1.0f;
        v *= adjb[(size_t)row * M + col];
        Pb[(size_t)row * M + col] = f2bf(v);
      }
}

// ---- K6: 128-tile GEMM for the skinny P@Y products (EPI 1: relu+bias f32,
//          EPI 2: bias f32). A MxK bf16, B = N-rows x K bf16. ----
template <int EPI>
__global__ __launch_bounds__(256) void k_gemm(
    const u16* __restrict__ A, size_t sA, int ldA,
    const u16* __restrict__ Bm, size_t sB, int ldB,
    int M, int K, int Nrows, int Ncols,
    const float* __restrict__ bias, float* __restrict__ Fout, int b0) {
  __shared__ __align__(16) u16 As[2][128 * 32];
  __shared__ __align__(16) u16 Bs[2][128 * 32];
  const int bi = blockIdx.z, bg = b0 + bi;
  const u16* Ab = A + (size_t)bi * sA;
  const u16* Bb = Bm + (size_t)bg * sB;
  const int tm = blockIdx.y * 128, tn = blockIdx.x * 128;
  const int tid = threadIdx.x, w = tid >> 6, l = tid & 63;
  const int wm = (w >> 1) * 64, wn = (w & 1) * 64;
  const int lr = l & 15, kg = (l >> 4) * 8;
  const int chunk = l & 3;
  int arow[2], brow[2];
  #pragma unroll
  for (int i = 0; i < 2; ++i) {
    int r = (i * 4 + w) * 16 + (l >> 2);
    arow[i] = tm + r;
    int rb = tn + r;
    brow[i] = rb < Nrows ? rb : Nrows - 1;
  }
  f32x4_t acc[4][4];
  const f32x4_t zv = {0.f, 0.f, 0.f, 0.f};
  #pragma unroll
  for (int m = 0; m < 4; ++m)
    #pragma unroll
    for (int n = 0; n < 4; ++n) acc[m][n] = zv;

  auto stage = [&](int buf, int k0) {
    #pragma unroll
    for (int i = 0; i < 2; ++i) {
      gload_lds16(Ab + (size_t)arow[i] * ldA + k0 + chunk * 8,
                  (char*)As[buf] + (i * 4 + w) * 1024);
      gload_lds16(Bb + (size_t)brow[i] * ldB + k0 + chunk * 8,
                  (char*)Bs[buf] + (i * 4 + w) * 1024);
    }
  };

  const int nsteps = K >> 5;
  stage(0, 0);
  __syncthreads();
  for (int s = 0; s < nsteps; ++s) {
    const int cur = s & 1;
    if (s + 1 < nsteps) stage(cur ^ 1, (s + 1) << 5);
    bf16x8_t af[4], bfr[4];
    #pragma unroll
    for (int m = 0; m < 4; ++m) af[m] = *(const bf16x8_t*)&As[cur][(wm + m * 16 + lr) * 32 + kg];
    #pragma unroll
    for (int n = 0; n < 4; ++n) bfr[n] = *(const bf16x8_t*)&Bs[cur][(wn + n * 16 + lr) * 32 + kg];
    #pragma unroll
    for (int m = 0; m < 4; ++m)
      #pragma unroll
      for (int n = 0; n < 4; ++n)
        acc[m][n] = __builtin_amdgcn_mfma_f32_16x16x32_bf16(af[m], bfr[n], acc[m][n], 0, 0, 0);
    __syncthreads();
  }

  float* Ob = Fout + (size_t)bg * M * Ncols;
  #pragma unroll
  for (int m = 0; m < 4; ++m)
    #pragma unroll
    for (int n = 0; n < 4; ++n)
      #pragma unroll
      for (int q = 0; q < 4; ++q) {
        int row = tm + wm + m * 16 + (l >> 4) * 4 + q;
        int col = tn + wn + n * 16 + lr;
        if (col < Ncols) {
          float v = acc[m][n][q] + bias[col];
          if (EPI == 1) v = fmaxf(v, 0.f);
          Ob[(size_t)row * Ncols + col] = v;
        }
      }
}

// ---- K4: c[bg, j] = max_i P[bi, i, j]  (row-sliced, atomicMax on float bits) ----
__global__ void k_colmax(const u16* __restrict__ P, unsigned int* __restrict__ c,
                         int M, int N, int rowsPer, int b0) {
  const int bi = blockIdx.z, bg = b0 + bi;
  const u16* Pb = P + (size_t)bi * (size_t)M * N;
  const int j = (blockIdx.x * 256 + threadIdx.x) * 4;
  const int r0 = blockIdx.y * rowsPer;
  float m0 = 0.f, m1 = 0.f, m2 = 0.f, m3 = 0.f;
  for (int i = r0; i < r0 + rowsPer; ++i) {
    uint2 v = *(const uint2*)(Pb + (size_t)i * N + j);
    m0 = fmaxf(m0, bf2f(v.x & 0xffff)); m1 = fmaxf(m1, bf2f(v.x >> 16));
    m2 = fmaxf(m2, bf2f(v.y & 0xffff)); m3 = fmaxf(m3, bf2f(v.y >> 16));
  }
  unsigned int* cb = c + (size_t)bg * N;
  atomicMax(cb + j + 0, __float_as_uint(m0));
  atomicMax(cb + j + 1, __float_as_uint(m1));
  atomicMax(cb + j + 2, __float_as_uint(m2));
  atomicMax(cb + j + 3, __float_as_uint(m3));
}

// ---- K5: YT[bg, c, j] = bf16( (sum_k Xin[bg,j,k] W[k,c]) / cmax[bg,j] ) ----
template <bool RELU_IN>
__global__ __launch_bounds__(256) void k_smallgemm(
    const float* __restrict__ X, size_t sX, int Kd,
    const float* __restrict__ W, int Cc,
    const float* __restrict__ cmax, u16* __restrict__ YT, size_t sY,
    int Nj, int b0) {
  __shared__ float Xs[64][129];
  __shared__ float Ws[128][33];
  const int bg = b0 + blockIdx.y;
  const float* Xb = X + (size_t)bg * sX;
  const int j0 = blockIdx.x * 64;
  const int tid = threadIdx.x;
  for (int idx = tid; idx < 64 * (Kd / 4); idx += 256) {
    int r = idx / (Kd / 4), q = idx % (Kd / 4);
    float4 v = *(const float4*)(Xb + (size_t)(j0 + r) * Kd + q * 4);
    if (RELU_IN) {
      v.x = fmaxf(v.x, 0.f); v.y = fmaxf(v.y, 0.f);
      v.z = fmaxf(v.z, 0.f); v.w = fmaxf(v.w, 0.f);
    }
    Xs[r][q * 4 + 0] = v.x; Xs[r][q * 4 + 1] = v.y;
    Xs[r][q * 4 + 2] = v.z; Xs[r][q * 4 + 3] = v.w;
  }
  const int r = tid & 63, cg = tid >> 6;
  const float rinv = 1.0f / cmax[(size_t)bg * Nj + j0 + r];
  for (int c0 = 0; c0 < Cc; c0 += 32) {
    __syncthreads();
    for (int idx = tid; idx < Kd * 32; idx += 256) {
      int k = idx >> 5, c = c0 + (idx & 31);
      Ws[k][idx & 31] = (c < Cc) ? W[(size_t)k * Cc + c] : 0.f;
    }
    __syncthreads();
    float acc[8] = {0.f, 0.f, 0.f, 0.f, 0.f, 0.f, 0.f, 0.f};
    for (int k = 0; k < Kd; ++k) {
      float xv = Xs[r][k];
      #pragma unroll
      for (int cc = 0; cc < 8; ++cc) acc[cc] += xv * Ws[k][cg * 8 + cc];
    }
    #pragma unroll
    for (int cc = 0; cc < 8; ++cc) {
      int c = c0 + cg * 8 + cc;
      if (c < Cc) YT[(size_t)bg * sY + (size_t)c * Nj + j0 + r] = f2bf(acc[cc] * rinv);
    }
  }
}

extern "C" void kernel_launch(void* const* d_in, const int* in_sizes, int n_in,
                              void* d_out, int out_size, void* d_ws, size_t ws_size,
                              hipStream_t stream) {
  const float* X    = (const float*)d_in[0];
  const float* Z    = (const float*)d_in[1];
  const float* adje = (const float*)d_in[2];
  const float* adjv = (const float*)d_in[3];
  const float* T    = (const float*)d_in[4];
  const float* W1   = (const float*)d_in[5];
  const float* b1   = (const float*)d_in[6];
  const float* p1   = (const float*)d_in[7];
  const float* W2   = (const float*)d_in[8];
  const float* b2   = (const float*)d_in[9];
  const float* p2   = (const float*)d_in[10];
  const float* W3   = (const float*)d_in[11];
  const float* b3   = (const float*)d_in[12];
  const float* p3   = (const float*)d_in[13];
  float* out = (float*)d_out;
  (void)in_sizes; (void)n_in; (void)out_size;

  hipFuncSetAttribute(reinterpret_cast<const void*>(k_gemm256),
                      hipFuncAttributeMaxDynamicSharedMemorySize, 131072);

  char* ws = (char*)d_ws;
  size_t off = 0;
  auto alloc = [&](size_t n) -> char* {
    char* p = ws + off; off = (off + n + 255) & ~(size_t)255; return p;
  };
  u16* Tbf    = (u16*)alloc((size_t)NBATCH * NV * NE * 2);
  u16* Ttbf   = (u16*)alloc((size_t)NBATCH * NE * NV * 2);
  float* dbuf = (float*)alloc((size_t)NBATCH * NE * 4);
  float* cbuf = (float*)alloc((size_t)NBATCH * NE * 4);
  u16* YT     = (u16*)alloc((size_t)NBATCH * NE * 64 * 2);
  float* x1   = (float*)alloc((size_t)NBATCH * NV * HID * 4);
  float* z2   = (float*)alloc((size_t)NBATCH * NE * FE * 4);
  const size_t needA = (size_t)NBATCH * NV * NE * 2;
  const size_t needP = (size_t)NBATCH * NE * NE * 2;
  const bool full = (ws_size >= off + needA + needP + 1024);
  const int nb = full ? NBATCH : 1;
  u16* Asc = (u16*)alloc(full ? needA : (size_t)NV * NE * 2);
  u16* P   = (u16*)alloc(full ? needP : (size_t)NE * NE * 2);

  const dim3 blk(256, 1, 1);
  const dim3 blk512(512, 1, 1);
  const size_t cbytes = (size_t)NBATCH * NE * 4;

  k_transpose<<<dim3(NE / 32, NV / 32, NBATCH), blk, 0, stream>>>(T, Tbf, Ttbf);

  // ---------------- Layer 1 (node: Fv -> H) ----------------
  k_rowdot<<<dim3(NE / 4, NBATCH), blk, 0, stream>>>(Z, p1, dbuf, NE, FE);
  for (int b0 = 0; b0 < NBATCH; b0 += nb) {
    k_scale<true><<<dim3((NV * NE) / 2048, nb), blk, 0, stream>>>(Tbf, dbuf, Asc, NE, b0);
    k_gemm256<<<dim3(NV / 256, NV / 256, nb), blk512, 131072, stream>>>(
        Asc, (size_t)NV * NE, NE, Tbf, (size_t)NV * NE, NE, NV, NE, adjv, P, b0);
    hipMemsetAsync(cbuf, 0, cbytes, stream);
    k_colmax<<<dim3(NV / 1024, NV / 32, nb), blk, 0, stream>>>(
        P, (unsigned int*)cbuf, NV, NV, 32, b0);
    k_smallgemm<false><<<dim3(NV / 64, nb), blk, 0, stream>>>(
        X, (size_t)NV * FV, FV, W1, HID, cbuf, YT, (size_t)NV * HID, NV, b0);
    k_gemm<1><<<dim3(1, NV / 128, nb), blk, 0, stream>>>(
        P, (size_t)NV * NV, NV, YT, (size_t)NV * HID, NV,
        NV, NV, HID, HID, b1, x1, b0);
  }
  // ---------------- Layer 2 (edge: Fe -> Fe) ----------------
  k_rowdot<<<dim3(NV / 4, NBATCH), blk, 0, stream>>>(x1, p2, dbuf, NV, HID);
  for (int b0 = 0; b0 < NBATCH; b0 += nb) {
    k_scale<true><<<dim3((NE * NV) / 2048, nb), blk, 0, stream>>>(Ttbf, dbuf, Asc, NV, b0);
    k_gemm256<<<dim3(NE / 256, NE / 256, nb), blk512, 131072, stream>>>(
        Asc, (size_t)NE * NV, NV, Ttbf, (size_t)NE * NV, NV, NE, NV, adje, P, b0);
    hipMemsetAsync(cbuf, 0, cbytes, stream);
    k_colmax<<<dim3(NE / 1024, NE / 64, nb), blk, 0, stream>>>(
        P, (unsigned int*)cbuf, NE, NE, 64, b0);
    k_smallgemm<true><<<dim3(NE / 64, nb), blk, 0, stream>>>(
        Z, (size_t)NE * FE, FE, W2, FE, cbuf, YT, (size_t)NE * FE, NE, b0);
    k_gemm<1><<<dim3(1, NE / 128, nb), blk, 0, stream>>>(
        P, (size_t)NE * NE, NE, YT, (size_t)NE * FE, NE,
        NE, NE, FE, FE, b2, z2, b0);
  }
  // ---------------- Layer 3 (node: H -> C) ----------------
  k_rowdot<<<dim3(NE / 4, NBATCH), blk, 0, stream>>>(z2, p3, dbuf, NE, FE);
  for (int b0 = 0; b0 < NBATCH; b0 += nb) {
    k_scale<true><<<dim3((NV * NE) / 2048, nb), blk, 0, stream>>>(Tbf, dbuf, Asc, NE, b0);
    k_gemm256<<<dim3(NV / 256, NV / 256, nb), blk512, 131072, stream>>>(
        Asc, (size_t)NV * NE, NE, Tbf, (size_t)NV * NE, NE, NV, NE, adjv, P, b0);
    hipMemsetAsync(cbuf, 0, cbytes, stream);
    k_colmax<<<dim3(NV / 1024, NV / 32, nb), blk, 0, stream>>>(
        P, (unsigned int*)cbuf, NV, NV, 32, b0);
    k_smallgemm<false><<<dim3(NV / 64, nb), blk, 0, stream>>>(
        x1, (size_t)NV * HID, HID, W3, NCLS, cbuf, YT, (size_t)NV * NCLS, NV, b0);
    k_gemm<2><<<dim3(1, NV / 128, nb), blk, 0, stream>>>(
        P, (size_t)NV * NV, NV, YT, (size_t)NV * NCLS, NV,
        NV, NV, NCLS, NCLS, b3, out, b0);
  }
}

// Round 6
// 659.693 us; speedup vs baseline: 3.6403x; 1.1140x over previous
//
#include <hip/hip_runtime.h>
#include <hip/hip_bf16.h>
#include <stdint.h>

#define DEVI __device__ __forceinline__

typedef __bf16 bf16x8_t __attribute__((ext_vector_type(8)));
typedef float f32x4_t __attribute__((ext_vector_type(4)));
typedef unsigned short u16;

static constexpr int NBATCH = 16;
static constexpr int NV = 1024;
static constexpr int NE = 2048;
static constexpr int FV = 128;
static constexpr int FE = 64;
static constexpr int HID = 128;
static constexpr int NCLS = 16;

DEVI u16 f2bf(float f) { __hip_bfloat16 h = __float2bfloat16(f); return *reinterpret_cast<u16*>(&h); }
DEVI float bf2f(u16 u) { union { unsigned int i; float f; } x; x.i = ((unsigned int)u) << 16; return x.f; }

DEVI void gload_lds16(const void* g, void* l) {
  __builtin_amdgcn_global_load_lds(
      (const __attribute__((address_space(1))) unsigned int*)g,
      (__attribute__((address_space(3))) unsigned int*)l, 16, 0, 0);
}

// ---- K0: T (f32) -> T_bf + Tt_bf; optionally fused Asc1 = T * d1[col] ----
template <bool WRITE_ASC>
__global__ void k_transpose(const float* __restrict__ T, u16* __restrict__ Tbf,
                            u16* __restrict__ Ttbf, const float* __restrict__ d1,
                            u16* __restrict__ Asc1) {
  __shared__ u16 s[32][33];
  const int b = blockIdx.z;
  const int e0 = blockIdx.x * 32, v0 = blockIdx.y * 32;
  const float* Tb = T + (size_t)b * NV * NE;
  u16* T1 = Tbf + (size_t)b * NV * NE;
  u16* T2 = Ttbf + (size_t)b * NE * NV;
  const int tx = threadIdx.x & 31, ty = threadIdx.x >> 5;
  float dv = 0.f;
  if (WRITE_ASC) dv = d1[(size_t)b * NE + e0 + tx];
  #pragma unroll
  for (int i = 0; i < 4; ++i) {
    int v = v0 + ty + i * 8;
    float f = Tb[(size_t)v * NE + e0 + tx];
    u16 u = f2bf(f);
    T1[(size_t)v * NE + e0 + tx] = u;
    if (WRITE_ASC) Asc1[(size_t)b * NV * NE + (size_t)v * NE + e0 + tx] = f2bf(f * dv);
    s[ty + i * 8][tx] = u;
  }
  __syncthreads();
  #pragma unroll
  for (int i = 0; i < 4; ++i) {
    int e = e0 + ty + i * 8;
    T2[(size_t)e * NV + v0 + tx] = s[tx][ty + i * 8];
  }
}

// ---- K1: d[b,r] = sum_c In[b,r,c] * p[c] ---- (one wave per row)
__global__ void k_rowdot(const float* __restrict__ In, const float* __restrict__ p,
                         float* __restrict__ d, int R, int C) {
  const int b = blockIdx.y;
  const int w = threadIdx.x >> 6, l = threadIdx.x & 63;
  const int r = blockIdx.x * 4 + w;
  const float* row = In + ((size_t)b * R + r) * C;
  float s = 0.f;
  for (int c = l; c < C; c += 64) s += row[c] * p[c];
  #pragma unroll
  for (int o = 32; o; o >>= 1) s += __shfl_xor(s, o);
  if (l == 0) d[(size_t)b * R + r] = s;
}

// ---- K2: Asc[bi, r, k] = In[bg, r, k] * d[bg, k]  (bf16 in/out) ----
__global__ void k_scale(const u16* __restrict__ In, const float* __restrict__ d,
                        u16* __restrict__ Out, int K, int b0) {
  const int bi = blockIdx.y, bg = b0 + bi;
  const size_t elems = (size_t)NV * NE;
  const size_t idx = ((size_t)blockIdx.x * 256 + threadIdx.x) * 8;
  const float* dd = d + (size_t)bg * K;
  const int k = (int)(idx & (size_t)(K - 1));
  const u16* in = In + (size_t)bg * elems + idx;
  uint4 raw = *(const uint4*)in;
  float f[8];
  f[0] = bf2f(raw.x & 0xffff); f[1] = bf2f(raw.x >> 16);
  f[2] = bf2f(raw.y & 0xffff); f[3] = bf2f(raw.y >> 16);
  f[4] = bf2f(raw.z & 0xffff); f[5] = bf2f(raw.z >> 16);
  f[6] = bf2f(raw.w & 0xffff); f[7] = bf2f(raw.w >> 16);
  u16 o[8];
  #pragma unroll
  for (int t = 0; t < 8; ++t) o[t] = f2bf(f[t] * dd[k + t]);
  *(uint4*)((u16*)Out + (size_t)bi * elems + idx) = *(uint4*)o;
}

// ---- K3: 256x256-tile GEMM  P[bi] = (diag?1:A*B^T) * adj[bg]  (bf16 out) ----
// Round-4 schedule (measured best): stage(next) early, 1 barrier per K-tile,
// T2 XOR swizzle via inverse-swizzled source, XCD swizzle, setprio on MFMA.
// Epilogue additionally produces per-block column maxima (no atomics):
// pmax[bi][by][col] = max over this block's 256 rows of P[row][col].
__global__ __launch_bounds__(512, 2) void k_gemm256(
    const u16* __restrict__ A, size_t sA, int ldA,
    const u16* __restrict__ Bm, size_t sB, int ldB,
    int M, int K,
    const float* __restrict__ adj, u16* __restrict__ Pout,
    float* __restrict__ pmax, int b0) {
  extern __shared__ __align__(16) char smem[];
  const int gx = gridDim.x, gy = gridDim.y;
  const int total = gx * gy * gridDim.z;
  int orig = blockIdx.x + gx * (blockIdx.y + gy * blockIdx.z);
  const int cpx = total >> 3;
  int swz = (orig & 7) * cpx + (orig >> 3);
  const int bx = swz % gx;
  const int by = (swz / gx) % gy;
  const int bi = swz / (gx * gy);
  const int bg = b0 + bi;

  const u16* Ab = A + (size_t)bi * sA;
  const u16* Bb = Bm + (size_t)bg * sB;
  const int tm = by * 256, tn = bx * 256;
  const int tid = threadIdx.x, wid = tid >> 6, l = tid & 63;
  const int wr = wid >> 2, wc = wid & 3;

  const int srow = tid >> 3;
  const int scol = (((tid & 7) ^ (srow & 7)) << 3);

  const int Lx = (l & 7) << 4;
  const int colb0 = (((l >> 4) << 4)) ^ Lx;
  const int colb1 = (64 + ((l >> 4) << 4)) ^ Lx;
  const int arowb = (wr * 128 + (l & 15)) * 128;
  const int browb = (wc * 64 + (l & 15)) * 128;

  auto stage = [&](int buf, int k0) {
    char* ab = smem + (buf << 16);
    char* bb = ab + 32768;
    #pragma unroll
    for (int ld2 = 0; ld2 < 4; ++ld2) {
      gload_lds16(Ab + (size_t)(tm + ld2 * 64 + srow) * ldA + (k0 + scol),
                  ab + ld2 * 8192 + tid * 16);
      gload_lds16(Bb + (size_t)(tn + ld2 * 64 + srow) * ldB + (k0 + scol),
                  bb + ld2 * 8192 + tid * 16);
    }
  };

  f32x4_t acc[8][4];
  const f32x4_t zv = {0.f, 0.f, 0.f, 0.f};
  #pragma unroll
  for (int m = 0; m < 8; ++m)
    #pragma unroll
    for (int n = 0; n < 4; ++n) acc[m][n] = zv;

  const int NT = K >> 6;
  stage(0, 0);
  __syncthreads();

  for (int kt = 0; kt < NT; ++kt) {
    const int buf = kt & 1;
    if (kt + 1 < NT) stage(buf ^ 1, (kt + 1) << 6);
    char* abase = smem + (buf << 16);
    char* bbase = abase + 32768;
    bf16x8_t af[4][2], bfr[4][2];
    #pragma unroll
    for (int m = 0; m < 4; ++m) {
      af[m][0] = *(const bf16x8_t*)(abase + arowb + m * 2048 + colb0);
      af[m][1] = *(const bf16x8_t*)(abase + arowb + m * 2048 + colb1);
    }
    #pragma unroll
    for (int n = 0; n < 2; ++n) {
      bfr[n][0] = *(const bf16x8_t*)(bbase + browb + n * 2048 + colb0);
      bfr[n][1] = *(const bf16x8_t*)(bbase + browb + n * 2048 + colb1);
    }
    __builtin_amdgcn_s_setprio(1);
    #pragma unroll
    for (int m = 0; m < 4; ++m)
      #pragma unroll
      for (int n = 0; n < 2; ++n)
        #pragma unroll
        for (int kk = 0; kk < 2; ++kk)
          acc[m][n] = __builtin_amdgcn_mfma_f32_16x16x32_bf16(af[m][kk], bfr[n][kk], acc[m][n], 0, 0, 0);
    __builtin_amdgcn_s_setprio(0);
    #pragma unroll
    for (int n = 2; n < 4; ++n) {
      bfr[n][0] = *(const bf16x8_t*)(bbase + browb + n * 2048 + colb0);
      bfr[n][1] = *(const bf16x8_t*)(bbase + browb + n * 2048 + colb1);
    }
    __builtin_amdgcn_s_setprio(1);
    #pragma unroll
    for (int m = 0; m < 4; ++m)
      #pragma unroll
      for (int n = 2; n < 4; ++n)
        #pragma unroll
        for (int kk = 0; kk < 2; ++kk)
          acc[m][n] = __builtin_amdgcn_mfma_f32_16x16x32_bf16(af[m][kk], bfr[n][kk], acc[m][n], 0, 0, 0);
    __builtin_amdgcn_s_setprio(0);
    #pragma unroll
    for (int m = 0; m < 4; ++m) {
      af[m][0] = *(const bf16x8_t*)(abase + arowb + (m + 4) * 2048 + colb0);
      af[m][1] = *(const bf16x8_t*)(abase + arowb + (m + 4) * 2048 + colb1);
    }
    __builtin_amdgcn_s_setprio(1);
    #pragma unroll
    for (int m = 0; m < 4; ++m)
      #pragma unroll
      for (int n = 2; n < 4; ++n)
        #pragma unroll
        for (int kk = 0; kk < 2; ++kk)
          acc[m + 4][n] = __builtin_amdgcn_mfma_f32_16x16x32_bf16(af[m][kk], bfr[n][kk], acc[m + 4][n], 0, 0, 0);
    __builtin_amdgcn_s_setprio(0);
    __builtin_amdgcn_s_setprio(1);
    #pragma unroll
    for (int m = 0; m < 4; ++m)
      #pragma unroll
      for (int n = 0; n < 2; ++n)
        #pragma unroll
        for (int kk = 0; kk < 2; ++kk)
          acc[m + 4][n] = __builtin_amdgcn_mfma_f32_16x16x32_bf16(af[m][kk], bfr[n][kk], acc[m + 4][n], 0, 0, 0);
    __builtin_amdgcn_s_setprio(0);
    __syncthreads();
  }

  // ---- epilogue: diag=1, * adj, bf16 store, per-block column max ----
  const float* adjb = adj + (size_t)bg * M * M;
  u16* Pb = Pout + (size_t)bi * (size_t)M * M;
  float vmax[4] = {0.f, 0.f, 0.f, 0.f};
  #pragma unroll
  for (int m = 0; m < 8; ++m)
    #pragma unroll
    for (int n = 0; n < 4; ++n)
      #pragma unroll
      for (int q = 0; q < 4; ++q) {
        int row = tm + wr * 128 + m * 16 + (l >> 4) * 4 + q;
        int col = tn + wc * 64 + n * 16 + (l & 15);
        float v = acc[m][n][q];
        if (row == col) v = 1.0f;
        v *= adjb[(size_t)row * M + col];
        vmax[n] = fmaxf(vmax[n], v);
        Pb[(size_t)row * M + col] = f2bf(v);
      }
  // lanes l, l^16, l^32, l^48 share a column -> shuffle reduce
  #pragma unroll
  for (int n = 0; n < 4; ++n) {
    vmax[n] = fmaxf(vmax[n], __shfl_xor(vmax[n], 16));
    vmax[n] = fmaxf(vmax[n], __shfl_xor(vmax[n], 32));
  }
  float* red = (float*)smem;  // [wr][wc][n][16]
  if (l < 16) {
    #pragma unroll
    for (int n = 0; n < 4; ++n)
      red[((wr * 4 + wc) * 4 + n) * 16 + l] = vmax[n];
  }
  __syncthreads();
  if (wr == 0 && l < 16) {
    #pragma unroll
    for (int n = 0; n < 4; ++n) {
      float a = red[((0 * 4 + wc) * 4 + n) * 16 + l];
      float b = red[((1 * 4 + wc) * 4 + n) * 16 + l];
      pmax[((size_t)bi * gy + by) * M + tn + wc * 64 + n * 16 + l] = fmaxf(a, b);
    }
  }
}

// ---- K4b: c[bg, j] = max_g pmax[bi, g, j] ----
__global__ void k_colmax2(const float* __restrict__ pmax, float* __restrict__ c,
                          int N, int G, int b0) {
  const int bi = blockIdx.y, bg = b0 + bi;
  const int j = blockIdx.x * 256 + threadIdx.x;
  const float* pb = pmax + (size_t)bi * G * N;
  float m = 0.f;
  for (int g = 0; g < G; ++g) m = fmaxf(m, pb[(size_t)g * N + j]);
  c[(size_t)bg * N + j] = m;
}

// ---- K6: 128-tile GEMM, BN=128 (layer-1 P@Yc, Ncols=128) ----
template <int EPI>
__global__ __launch_bounds__(256) void k_gemm(
    const u16* __restrict__ A, size_t sA, int ldA,
    const u16* __restrict__ Bm, size_t sB, int ldB,
    int M, int K, int Nrows, int Ncols,
    const float* __restrict__ bias, float* __restrict__ Fout, int b0) {
  __shared__ __align__(16) u16 As[2][128 * 32];
  __shared__ __align__(16) u16 Bs[2][128 * 32];
  const int bi = blockIdx.z, bg = b0 + bi;
  const u16* Ab = A + (size_t)bi * sA;
  const u16* Bb = Bm + (size_t)bg * sB;
  const int tm = blockIdx.y * 128, tn = blockIdx.x * 128;
  const int tid = threadIdx.x, w = tid >> 6, l = tid & 63;
  const int wm = (w >> 1) * 64, wn = (w & 1) * 64;
  const int lr = l & 15, kg = (l >> 4) * 8;
  const int chunk = l & 3;
  int arow[2], brow[2];
  #pragma unroll
  for (int i = 0; i < 2; ++i) {
    int r = (i * 4 + w) * 16 + (l >> 2);
    arow[i] = tm + r;
    int rb = tn + r;
    brow[i] = rb < Nrows ? rb : Nrows - 1;
  }
  f32x4_t acc[4][4];
  const f32x4_t zv = {0.f, 0.f, 0.f, 0.f};
  #pragma unroll
  for (int m = 0; m < 4; ++m)
    #pragma unroll
    for (int n = 0; n < 4; ++n) acc[m][n] = zv;

  auto stage = [&](int buf, int k0) {
    #pragma unroll
    for (int i = 0; i < 2; ++i) {
      gload_lds16(Ab + (size_t)arow[i] * ldA + k0 + chunk * 8,
                  (char*)As[buf] + (i * 4 + w) * 1024);
      gload_lds16(Bb + (size_t)brow[i] * ldB + k0 + chunk * 8,
                  (char*)Bs[buf] + (i * 4 + w) * 1024);
    }
  };

  const int nsteps = K >> 5;
  stage(0, 0);
  __syncthreads();
  for (int s = 0; s < nsteps; ++s) {
    const int cur = s & 1;
    if (s + 1 < nsteps) stage(cur ^ 1, (s + 1) << 5);
    bf16x8_t af[4], bfr[4];
    #pragma unroll
    for (int m = 0; m < 4; ++m) af[m] = *(const bf16x8_t*)&As[cur][(wm + m * 16 + lr) * 32 + kg];
    #pragma unroll
    for (int n = 0; n < 4; ++n) bfr[n] = *(const bf16x8_t*)&Bs[cur][(wn + n * 16 + lr) * 32 + kg];
    #pragma unroll
    for (int m = 0; m < 4; ++m)
      #pragma unroll
      for (int n = 0; n < 4; ++n)
        acc[m][n] = __builtin_amdgcn_mfma_f32_16x16x32_bf16(af[m], bfr[n], acc[m][n], 0, 0, 0);
    __syncthreads();
  }

  float* Ob = Fout + (size_t)bg * M * Ncols;
  #pragma unroll
  for (int m = 0; m < 4; ++m)
    #pragma unroll
    for (int n = 0; n < 4; ++n)
      #pragma unroll
      for (int q = 0; q < 4; ++q) {
        int row = tm + wm + m * 16 + (l >> 4) * 4 + q;
        int col = tn + wn + n * 16 + lr;
        if (col < Ncols) {
          float v = acc[m][n][q] + bias[col];
          if (EPI == 1) v = fmaxf(v, 0.f);
          Ob[(size_t)row * Ncols + col] = v;
        }
      }
}

// ---- K7: skinny 128x64-tile GEMM for P@Yc with Ncols<=64 (layers 2,3) ----
// 256 thr = 4 waves (2M x 2N), wave-tile 64x32, BK=32 double-buffered.
template <int EPI>
__global__ __launch_bounds__(256) void k_gemmPY(
    const u16* __restrict__ A, size_t sA, int ldA,
    const u16* __restrict__ Bm, size_t sB,
    int M, int K, int Ncols,
    const float* __restrict__ bias, float* __restrict__ Fout, int b0) {
  __shared__ __align__(16) u16 As[2][128 * 32];
  __shared__ __align__(16) u16 Bs[2][64 * 32];
  const int bi = blockIdx.z, bg = b0 + bi;
  const u16* Ab = A + (size_t)bi * sA;
  const u16* Bb = Bm + (size_t)bg * sB;
  const int tm = blockIdx.y * 128;
  const int tid = threadIdx.x, w = tid >> 6, l = tid & 63;
  const int wm = (w >> 1) * 64, wn = (w & 1) * 32;
  const int lr = l & 15, kg = (l >> 4) * 8;
  const int chunk = l & 3;
  int arow[2];
  #pragma unroll
  for (int i = 0; i < 2; ++i) arow[i] = tm + (i * 4 + w) * 16 + (l >> 2);
  const int brow = w * 16 + (l >> 2);  // rows 0..63 of B

  f32x4_t acc[4][2];
  const f32x4_t zv = {0.f, 0.f, 0.f, 0.f};
  #pragma unroll
  for (int m = 0; m < 4; ++m)
    #pragma unroll
    for (int n = 0; n < 2; ++n) acc[m][n] = zv;

  auto stage = [&](int buf, int k0) {
    #pragma unroll
    for (int i = 0; i < 2; ++i)
      gload_lds16(Ab + (size_t)arow[i] * ldA + k0 + chunk * 8,
                  (char*)As[buf] + (i * 4 + w) * 1024);
    gload_lds16(Bb + (size_t)brow * ldA /*ldB == K == ldA*/ + k0 + chunk * 8,
                (char*)Bs[buf] + tid * 16);
  };

  const int nsteps = K >> 5;
  stage(0, 0);
  __syncthreads();
  for (int s = 0; s < nsteps; ++s) {
    const int cur = s & 1;
    if (s + 1 < nsteps) stage(cur ^ 1, (s + 1) << 5);
    bf16x8_t af[4], bfr[2];
    #pragma unroll
    for (int m = 0; m < 4; ++m) af[m] = *(const bf16x8_t*)&As[cur][(wm + m * 16 + lr) * 32 + kg];
    #pragma unroll
    for (int n = 0; n < 2; ++n) bfr[n] = *(const bf16x8_t*)&Bs[cur][(wn + n * 16 + lr) * 32 + kg];
    #pragma unroll
    for (int m = 0; m < 4; ++m)
      #pragma unroll
      for (int n = 0; n < 2; ++n)
        acc[m][n] = __builtin_amdgcn_mfma_f32_16x16x32_bf16(af[m], bfr[n], acc[m][n], 0, 0, 0);
    __syncthreads();
  }

  float* Ob = Fout + (size_t)bg * M * Ncols;
  #pragma unroll
  for (int m = 0; m < 4; ++m)
    #pragma unroll
    for (int n = 0; n < 2; ++n)
      #pragma unroll
      for (int q = 0; q < 4; ++q) {
        int row = tm + wm + m * 16 + (l >> 4) * 4 + q;
        int col = wn + n * 16 + lr;
        if (col < Ncols) {
          float v = acc[m][n][q] + bias[col];
          if (EPI == 1) v = fmaxf(v, 0.f);
          Ob[(size_t)row * Ncols + col] = v;
        }
      }
}

// ---- K5: YT[bg, c, j] = bf16( (sum_k Xin[bg,j,k] W[k,c]) / cmax[bg,j] ) ----
template <bool RELU_IN>
__global__ __launch_bounds__(256) void k_smallgemm(
    const float* __restrict__ X, size_t sX, int Kd,
    const float* __restrict__ W, int Cc,
    const float* __restrict__ cmax, u16* __restrict__ YT, size_t sY,
    int Nj, int b0) {
  __shared__ float Xs[64][129];
  __shared__ float Ws[128][33];
  const int bg = b0 + blockIdx.y;
  const float* Xb = X + (size_t)bg * sX;
  const int j0 = blockIdx.x * 64;
  const int tid = threadIdx.x;
  for (int idx = tid; idx < 64 * (Kd / 4); idx += 256) {
    int r = idx / (Kd / 4), q = idx % (Kd / 4);
    float4 v = *(const float4*)(Xb + (size_t)(j0 + r) * Kd + q * 4);
    if (RELU_IN) {
      v.x = fmaxf(v.x, 0.f); v.y = fmaxf(v.y, 0.f);
      v.z = fmaxf(v.z, 0.f); v.w = fmaxf(v.w, 0.f);
    }
    Xs[r][q * 4 + 0] = v.x; Xs[r][q * 4 + 1] = v.y;
    Xs[r][q * 4 + 2] = v.z; Xs[r][q * 4 + 3] = v.w;
  }
  const int r = tid & 63, cg = tid >> 6;
  const float rinv = 1.0f / cmax[(size_t)bg * Nj + j0 + r];
  for (int c0 = 0; c0 < Cc; c0 += 32) {
    __syncthreads();
    for (int idx = tid; idx < Kd * 32; idx += 256) {
      int k = idx >> 5, c = c0 + (idx & 31);
      Ws[k][idx & 31] = (c < Cc) ? W[(size_t)k * Cc + c] : 0.f;
    }
    __syncthreads();
    float acc[8] = {0.f, 0.f, 0.f, 0.f, 0.f, 0.f, 0.f, 0.f};
    for (int k = 0; k < Kd; ++k) {
      float xv = Xs[r][k];
      #pragma unroll
      for (int cc = 0; cc < 8; ++cc) acc[cc] += xv * Ws[k][cg * 8 + cc];
    }
    #pragma unroll
    for (int cc = 0; cc < 8; ++cc) {
      int c = c0 + cg * 8 + cc;
      if (c < Cc) YT[(size_t)bg * sY + (size_t)c * Nj + j0 + r] = f2bf(acc[cc] * rinv);
    }
  }
}

extern "C" void kernel_launch(void* const* d_in, const int* in_sizes, int n_in,
                              void* d_out, int out_size, void* d_ws, size_t ws_size,
                              hipStream_t stream) {
  const float* X    = (const float*)d_in[0];
  const float* Z    = (const float*)d_in[1];
  const float* adje = (const float*)d_in[2];
  const float* adjv = (const float*)d_in[3];
  const float* T    = (const float*)d_in[4];
  const float* W1   = (const float*)d_in[5];
  const float* b1   = (const float*)d_in[6];
  const float* p1   = (const float*)d_in[7];
  const float* W2   = (const float*)d_in[8];
  const float* b2   = (const float*)d_in[9];
  const float* p2   = (const float*)d_in[10];
  const float* W3   = (const float*)d_in[11];
  const float* b3   = (const float*)d_in[12];
  const float* p3   = (const float*)d_in[13];
  float* out = (float*)d_out;
  (void)in_sizes; (void)n_in; (void)out_size;

  hipFuncSetAttribute(reinterpret_cast<const void*>(k_gemm256),
                      hipFuncAttributeMaxDynamicSharedMemorySize, 131072);

  char* ws = (char*)d_ws;
  size_t off = 0;
  auto alloc = [&](size_t n) -> char* {
    char* p = ws + off; off = (off + n + 255) & ~(size_t)255; return p;
  };
  u16* Tbf    = (u16*)alloc((size_t)NBATCH * NV * NE * 2);
  u16* Ttbf   = (u16*)alloc((size_t)NBATCH * NE * NV * 2);
  float* dbuf = (float*)alloc((size_t)NBATCH * NE * 4);
  float* cbuf = (float*)alloc((size_t)NBATCH * NE * 4);
  float* pmax = (float*)alloc((size_t)NBATCH * 8 * NE * 4);
  u16* YT     = (u16*)alloc((size_t)NBATCH * NE * 64 * 2);
  float* x1   = (float*)alloc((size_t)NBATCH * NV * HID * 4);
  float* z2   = (float*)alloc((size_t)NBATCH * NE * FE * 4);
  const size_t needA = (size_t)NBATCH * NV * NE * 2;
  const size_t needP = (size_t)NBATCH * NE * NE * 2;
  const bool full = (ws_size >= off + needA + needP + 1024);
  const int nb = full ? NBATCH : 1;
  u16* Asc = (u16*)alloc(full ? needA : (size_t)NV * NE * 2);
  u16* P   = (u16*)alloc(full ? needP : (size_t)NE * NE * 2);

  const dim3 blk(256, 1, 1);
  const dim3 blk512(512, 1, 1);

  // d1 must exist before the (fused) transpose
  k_rowdot<<<dim3(NE / 4, NBATCH), blk, 0, stream>>>(Z, p1, dbuf, NE, FE);
  if (full)
    k_transpose<true><<<dim3(NE / 32, NV / 32, NBATCH), blk, 0, stream>>>(
        T, Tbf, Ttbf, dbuf, Asc);
  else
    k_transpose<false><<<dim3(NE / 32, NV / 32, NBATCH), blk, 0, stream>>>(
        T, Tbf, Ttbf, nullptr, nullptr);

  // ---------------- Layer 1 (node: Fv -> H) ----------------
  for (int b0 = 0; b0 < NBATCH; b0 += nb) {
    if (!full)
      k_scale<<<dim3((NV * NE) / 2048, nb), blk, 0, stream>>>(Tbf, dbuf, Asc, NE, b0);
    k_gemm256<<<dim3(NV / 256, NV / 256, nb), blk512, 131072, stream>>>(
        Asc, (size_t)NV * NE, NE, Tbf, (size_t)NV * NE, NE, NV, NE, adjv, P, pmax, b0);
    k_colmax2<<<dim3(NV / 256, nb), blk, 0, stream>>>(pmax, cbuf, NV, NV / 256, b0);
    k_smallgemm<false><<<dim3(NV / 64, nb), blk, 0, stream>>>(
        X, (size_t)NV * FV, FV, W1, HID, cbuf, YT, (size_t)NV * HID, NV, b0);
    k_gemm<1><<<dim3(1, NV / 128, nb), blk, 0, stream>>>(
        P, (size_t)NV * NV, NV, YT, (size_t)NV * HID, NV,
        NV, NV, HID, HID, b1, x1, b0);
  }
  // ---------------- Layer 2 (edge: Fe -> Fe) ----------------
  k_rowdot<<<dim3(NV / 4, NBATCH), blk, 0, stream>>>(x1, p2, dbuf, NV, HID);
  for (int b0 = 0; b0 < NBATCH; b0 += nb) {
    k_scale<<<dim3((NE * NV) / 2048, nb), blk, 0, stream>>>(Ttbf, dbuf, Asc, NV, b0);
    k_gemm256<<<dim3(NE / 256, NE / 256, nb), blk512, 131072, stream>>>(
        Asc, (size_t)NE * NV, NV, Ttbf, (size_t)NE * NV, NV, NE, NV, adje, P, pmax, b0);
    k_colmax2<<<dim3(NE / 256, nb), blk, 0, stream>>>(pmax, cbuf, NE, NE / 256, b0);
    k_smallgemm<true><<<dim3(NE / 64, nb), blk, 0, stream>>>(
        Z, (size_t)NE * FE, FE, W2, FE, cbuf, YT, (size_t)NE * FE, NE, b0);
    k_gemmPY<1><<<dim3(1, NE / 128, nb), blk, 0, stream>>>(
        P, (size_t)NE * NE, NE, YT, (size_t)NE * FE,
        NE, NE, FE, b2, z2, b0);
  }
  // ---------------- Layer 3 (node: H -> C) ----------------
  k_rowdot<<<dim3(NE / 4, NBATCH), blk, 0, stream>>>(z2, p3, dbuf, NE, FE);
  for (int b0 = 0; b0 < NBATCH; b0 += nb) {
    k_scale<<<dim3((NV * NE) / 2048, nb), blk, 0, stream>>>(Tbf, dbuf, Asc, NE, b0);
    k_gemm256<<<dim3(NV / 256, NV / 256, nb), blk512, 131072, stream>>>(
        Asc, (size_t)NV * NE, NE, Tbf, (size_t)NV * NE, NE, NV, NE, adjv, P, pmax, b0);
    k_colmax2<<<dim3(NV / 256, nb), blk, 0, stream>>>(pmax, cbuf, NV, NV / 256, b0);
    k_smallgemm<false><<<dim3(NV / 64, nb), blk, 0, stream>>>(
        x1, (size_t)NV * HID, HID, W3, NCLS, cbuf, YT, (size_t)NV * NCLS, NV, b0);
    k_gemmPY<2><<<dim3(1, NV / 128, nb), blk, 0, stream>>>(
        P, (size_t)NV * NV, NV, YT, (size_t)NV * NCLS,
        NV, NV, NCLS, b3, out, b0);
  }
}